// Round 7
// baseline (539.188 us; speedup 1.0000x reference)
//
#include <hip/hip_runtime.h>
#include <hip/hip_bf16.h>

// Problem constants
#define B_      1024
#define CIN     9
#define T0_     2048
#define C1_     16
#define C2_     32
#define RT_     512
#define NNODES  (B_ * RT_)     // 524288
#define HID_    128
#define OUTF_   64

typedef __attribute__((ext_vector_type(8))) __bf16 bf16x8;
typedef __attribute__((ext_vector_type(4))) float f32x4;
typedef __attribute__((ext_vector_type(8))) unsigned short us8;

// ---------- helpers ----------
__device__ __forceinline__ float bf2f(unsigned short u) {
    union { unsigned int i; float f; } c; c.i = ((unsigned int)u) << 16; return c.f;
}
// round-half-up bf16 (2 ops)
__device__ __forceinline__ unsigned short f2bf1(float f) {
    union { float f; unsigned int i; } c; c.f = f;
    return (unsigned short)((c.i + 0x8000u) >> 16);
}
// packed pair: low short = bf16(lo), high short = bf16(hi); 2 adds + 1 v_perm
__device__ __forceinline__ unsigned int f2bf2(float lo, float hi) {
    union { float f; unsigned int i; } a, b; a.f = lo; b.f = hi;
    return __builtin_amdgcn_perm(b.i + 0x8000u, a.i + 0x8000u, 0x07060302u);
}
__device__ __forceinline__ bf16x8 pack8(const float* v) {
    union { bf16x8 h; unsigned int u[4]; } r;
    #pragma unroll
    for (int i = 0; i < 4; i++) r.u[i] = f2bf2(v[2 * i], v[2 * i + 1]);
    return r.h;
}
__device__ __forceinline__ float dinv_of(int r) {
    return (r == 0 || r == RT_ - 1) ? 0.70710678118f : 0.57735026919f;
}

// ---------- MEGAKERNEL: conv1+pool -> conv2+pool -> gcn1 -> gcn2 -> mean -> FC ----------
// One block per 128-node tile; weight fragments built in-block from raw fp32 (L2-hot);
// per-sample mean+FC done by the last-finishing block of each sample (atomic counter).
__global__ __launch_bounds__(256, 2) void mega(
    const float* __restrict__ x,             // [B][9][2048] fp32
    const float* __restrict__ w1c, const float* __restrict__ c1b,   // conv1 w/b
    const float* __restrict__ w2c, const float* __restrict__ c2b,   // conv2 w/b
    const float* __restrict__ g1w, const float* __restrict__ g1b,   // gcn1 w/b
    const float* __restrict__ g2w, const float* __restrict__ g2b,   // gcn2 w/b
    const float* __restrict__ fcw, const float* __restrict__ fcb,   // fc w/b
    float* __restrict__ accum,               // [B][128] fp32, pre-zeroed
    unsigned int* __restrict__ cnt,          // [B] u32, pre-zeroed
    float* __restrict__ outp)                // [B][64] fp32
{
    // LDS lifetime plan (bytes):
    //   xs    [0, 26496)      552*24 shorts          phases A,B
    //   As1   [0, 11520)      144*40 shorts          phases D,E
    //   y2loc [11520, 19968)  132*32 shorts          phases C,D
    //   A2    [0, 38912)      128*152 shorts         phases F,G
    //   y1ext [39424, 48384)  280*16 shorts          phases B,C
    //   H     [39424, 74784)  130*136 shorts         phases E,F
    //   bls1  [74784, 75296); bls2 [75296, 75808)
    //   finisher: smf fp32[128] @0, flag int @512    (A2 dead by then)
    __shared__ __align__(16) unsigned char lds[75808];
    unsigned short* xs    = (unsigned short*)(lds);
    unsigned short* As1   = (unsigned short*)(lds);
    unsigned short* y2loc = (unsigned short*)(lds + 11520);
    unsigned short* A2    = (unsigned short*)(lds);
    unsigned short* y1ext = (unsigned short*)(lds + 39424);
    unsigned short* H     = (unsigned short*)(lds + 39424);
    float* bls1 = (float*)(lds + 74784);
    float* bls2 = (float*)(lds + 75296);

    const int tid = threadIdx.x;
    const int b = blockIdx.x >> 2;
    const int r0 = (blockIdx.x & 3) * 128;
    if (tid < 128) { bls1[tid] = g1b[tid]; bls2[tid] = g2b[tid]; }

    const int lane = tid & 63, wave = tid >> 6;
    const int m = lane & 15, q = lane >> 4;

    // ---- build conv weight fragments from raw fp32 (L2-hot; overlaps phase A loads)
    bf16x8 wfB[3];        // conv1 B-frags: kk=ks*32+q*8+j -> ktap=kk>>4, ci=kk&15, co=m
    #pragma unroll
    for (int ks = 0; ks < 3; ks++) {
        float v[8];
        #pragma unroll
        for (int j = 0; j < 8; j++) {
            int kk = ks * 32 + q * 8 + j, kt = kk >> 4, ci = kk & 15;
            v[j] = (kt < 5 && ci < CIN) ? w1c[(m * CIN + ci) * 5 + kt] : 0.f;
        }
        wfB[ks] = pack8(v);
    }
    bf16x8 wfC[3][2];     // conv2 B-frags: co=nt*16+m
    #pragma unroll
    for (int ks = 0; ks < 3; ks++)
        #pragma unroll
        for (int nt = 0; nt < 2; nt++) {
            float v[8];
            #pragma unroll
            for (int j = 0; j < 8; j++) {
                int kk = ks * 32 + q * 8 + j, kt = kk >> 4, ci = kk & 15;
                v[j] = (kt < 5) ? w2c[((nt * 16 + m) * C1_ + ci) * 5 + kt] : 0.f;
            }
            wfC[ks][nt] = pack8(v);
        }

    // ---- phase A: stage x as bf16 time-major: xs[s][ci], s=0..551, xt=4r0-14+s
    {
        const float* xb = x + (size_t)b * CIN * T0_;
        const int xbase = 4 * r0 - 14;
        for (int s = tid; s < 552; s += 256) {
            const int xt = xbase + s;
            union { us8 v; unsigned int u[4]; } o0, o1;
            if (xt >= 0 && xt < T0_) {
                float xv[9];
                #pragma unroll
                for (int ci = 0; ci < 9; ci++) xv[ci] = xb[ci * T0_ + xt];
                o0.u[0] = f2bf2(xv[0], xv[1]); o0.u[1] = f2bf2(xv[2], xv[3]);
                o0.u[2] = f2bf2(xv[4], xv[5]); o0.u[3] = f2bf2(xv[6], xv[7]);
                o1.u[0] = f2bf2(xv[8], 0.f);   o1.u[1] = o1.u[2] = o1.u[3] = 0;
            } else {
                o0.u[0] = o0.u[1] = o0.u[2] = o0.u[3] = 0;
                o1.u[0] = o1.u[1] = o1.u[2] = o1.u[3] = 0;
            }
            *(us8*)(xs + s * 24) = o0.v;
            *(us8*)(xs + s * 24 + 8) = o1.v;
        }
    }
    __syncthreads();

    // ---- phase B: conv1 MFMA + relu + pool -> y1ext (zero for t1 outside [0,1024))
    {
        const float bv = c1b[m];
        const int t1base = 2 * r0 - 6;
        for (int mt = wave; mt < 34; mt += 4) {
            f32x4 acc = {};
            #pragma unroll
            for (int ks = 0; ks < 3; ks++) {
                const int row = mt * 16 + m + ks * 2 + (q >> 1);
                const bf16x8 af = *(const bf16x8*)(xs + row * 24 + (q & 1) * 8);
                acc = __builtin_amdgcn_mfma_f32_16x16x32_bf16(af, wfB[ks], acc, 0, 0, 0);
            }
            const int prow = mt * 8 + q * 2;     // y1ext row; t1 = t1base + prow
            const int t1a = t1base + prow, t1b = t1a + 1;
            const float p0 = fmaxf(fmaxf(acc[0], acc[1]) + bv, 0.f);
            const float p1 = fmaxf(fmaxf(acc[2], acc[3]) + bv, 0.f);
            if (prow < 268)
                y1ext[prow * 16 + m] = (t1a >= 0 && t1a < 1024) ? f2bf1(p0) : (unsigned short)0;
            if (prow + 1 < 268)
                y1ext[(prow + 1) * 16 + m] = (t1b >= 0 && t1b < 1024) ? f2bf1(p1) : (unsigned short)0;
        }
        for (int idx = tid; idx < 192; idx += 256) y1ext[268 * 16 + idx] = 0;
    }
    __syncthreads();

    // ---- phase C: conv2 MFMA + relu + pool -> y2loc (132 nodes: r0-2 .. r0+129)
    {
        const float bv0 = c2b[m], bv1 = c2b[16 + m];
        for (int mt = wave; mt < 17; mt += 4) {
            f32x4 a0 = {}, a1 = {};
            #pragma unroll
            for (int ks = 0; ks < 3; ks++) {
                const int row = mt * 16 + m + ks * 2 + (q >> 1);
                const bf16x8 af = *(const bf16x8*)(y1ext + row * 16 + (q & 1) * 8);
                a0 = __builtin_amdgcn_mfma_f32_16x16x32_bf16(af, wfC[ks][0], a0, 0, 0, 0);
                a1 = __builtin_amdgcn_mfma_f32_16x16x32_bf16(af, wfC[ks][1], a1, 0, 0, 0);
            }
            const int nrow = mt * 8 + q * 2;
            if (nrow < 132) {
                y2loc[nrow * 32 + m]      = f2bf1(fmaxf(fmaxf(a0[0], a0[1]) + bv0, 0.f));
                y2loc[nrow * 32 + 16 + m] = f2bf1(fmaxf(fmaxf(a1[0], a1[1]) + bv1, 0.f));
            }
            if (nrow + 1 < 132) {
                y2loc[(nrow + 1) * 32 + m]      = f2bf1(fmaxf(fmaxf(a0[2], a0[3]) + bv0, 0.f));
                y2loc[(nrow + 1) * 32 + 16 + m] = f2bf1(fmaxf(fmaxf(a1[2], a1[3]) + bv1, 0.f));
            }
        }
    }
    // build gcn1 A-frags (W1^T) while conv2 results drain: k=q*8+j, f=ft*16+m
    bf16x8 wfE[2];
    {
        const int ft0 = wave * 2;
        #pragma unroll
        for (int i = 0; i < 2; i++) {
            float v[8];
            #pragma unroll
            for (int j = 0; j < 8; j++)
                v[j] = g1w[(q * 8 + j) * 128 + (ft0 + i) * 16 + m];
            wfE[i] = pack8(v);
        }
    }
    __syncthreads();

    // ---- phase D (gcn step1): As1 row i <-> node r0-1+i (i<130), stencil from y2loc
    for (int s = tid; s < 288; s += 256) {
        const int i = s >> 1, fh = (s & 1) * 16;
        unsigned short* dst = As1 + i * 40 + fh;
        const int r = r0 - 1 + i;
        union { us8 v; unsigned int u[4]; } o0, o1;
        if (i >= 130 || r < 0 || r >= RT_) {
            o0.u[0] = o0.u[1] = o0.u[2] = o0.u[3] = 0;
            o1.u[0] = o1.u[1] = o1.u[2] = o1.u[3] = 0;
        } else {
            const float dm = dinv_of(r), cm = dm * dm;
            const unsigned short* Yc = y2loc + (i + 1) * 32 + fh;
            us8 c0 = *(const us8*)(Yc), c1 = *(const us8*)(Yc + 8);
            float v[16];
            #pragma unroll
            for (int j = 0; j < 8; j++) { v[j] = cm * bf2f(c0[j]); v[8 + j] = cm * bf2f(c1[j]); }
            if (r > 0) {
                const float cl = dm * dinv_of(r - 1);
                us8 a0 = *(const us8*)(Yc - 32), a1 = *(const us8*)(Yc - 24);
                #pragma unroll
                for (int j = 0; j < 8; j++) { v[j] += cl * bf2f(a0[j]); v[8 + j] += cl * bf2f(a1[j]); }
            }
            if (r < RT_ - 1) {
                const float cr = dm * dinv_of(r + 1);
                us8 a0 = *(const us8*)(Yc + 32), a1 = *(const us8*)(Yc + 40);
                #pragma unroll
                for (int j = 0; j < 8; j++) { v[j] += cr * bf2f(a0[j]); v[8 + j] += cr * bf2f(a1[j]); }
            }
            #pragma unroll
            for (int i2 = 0; i2 < 4; i2++) {
                o0.u[i2] = f2bf2(v[2 * i2], v[2 * i2 + 1]);
                o1.u[i2] = f2bf2(v[8 + 2 * i2], v[9 + 2 * i2]);
            }
        }
        *(us8*)dst = o0.v; *(us8*)(dst + 8) = o1.v;
    }
    // build gcn2 B-frags during phase D: k=ks*32+q*8+j, f=ct*16+m
    bf16x8 bw[4][2];
    #pragma unroll
    for (int ks = 0; ks < 4; ks++)
        #pragma unroll
        for (int i = 0; i < 2; i++) {
            float v[8];
            #pragma unroll
            for (int j = 0; j < 8; j++)
                v[j] = g2w[(ks * 32 + q * 8 + j) * 128 + (wave * 2 + i) * 16 + m];
            bw[ks][i] = pack8(v);
        }
    __syncthreads();

    // ---- phase E (gcn1 MFMA): H = relu(As1 @ W1 + b1), rows 0..129
    {
        const int ft0 = wave * 2;
        const float4 bv0 = *(const float4*)&bls1[ft0 * 16 + q * 4];
        const float4 bv1 = *(const float4*)&bls1[(ft0 + 1) * 16 + q * 4];
        #pragma unroll
        for (int nt = 0; nt < 9; nt++) {
            const bf16x8 bfr = *(const bf16x8*)(As1 + (nt * 16 + m) * 40 + q * 8);
            f32x4 a0 = {}, a1 = {};
            a0 = __builtin_amdgcn_mfma_f32_16x16x32_bf16(wfE[0], bfr, a0, 0, 0, 0);
            a1 = __builtin_amdgcn_mfma_f32_16x16x32_bf16(wfE[1], bfr, a1, 0, 0, 0);
            const int row = nt * 16 + m;
            if (row < 130) {
                union { ushort4 s; unsigned int u[2]; } o0, o1;
                o0.u[0] = f2bf2(fmaxf(a0[0] + bv0.x, 0.f), fmaxf(a0[1] + bv0.y, 0.f));
                o0.u[1] = f2bf2(fmaxf(a0[2] + bv0.z, 0.f), fmaxf(a0[3] + bv0.w, 0.f));
                o1.u[0] = f2bf2(fmaxf(a1[0] + bv1.x, 0.f), fmaxf(a1[1] + bv1.y, 0.f));
                o1.u[1] = f2bf2(fmaxf(a1[2] + bv1.z, 0.f), fmaxf(a1[3] + bv1.w, 0.f));
                *(ushort4*)(H + row * 136 + ft0 * 16 + q * 4) = o0.s;
                *(ushort4*)(H + row * 136 + (ft0 + 1) * 16 + q * 4) = o1.s;
            }
        }
    }
    __syncthreads();

    // ---- phase F (gcn step3): A2[j] = cm*H[j+1] + cl*H[j] + cr*H[j+2], j=0..127
    {
        const int j = tid >> 1, fh = (tid & 1) * 64;
        const int r = r0 + j;
        const float dm = dinv_of(r), cm = dm * dm;
        const float cl = (r > 0) ? dm * dinv_of(r - 1) : 0.f;
        const float cr = (r < RT_ - 1) ? dm * dinv_of(r + 1) : 0.f;
        const unsigned short* Hl = H + j * 136 + fh;
        const unsigned short* Hc = Hl + 136;
        const unsigned short* Hr = Hc + 136;
        unsigned short* dst = A2 + j * 152 + fh;
        #pragma unroll
        for (int c = 0; c < 8; c++) {
            us8 cc = *(const us8*)(Hc + c * 8);
            us8 ll = *(const us8*)(Hl + c * 8);
            us8 rr = *(const us8*)(Hr + c * 8);
            float v[8];
            #pragma unroll
            for (int e = 0; e < 8; e++)
                v[e] = cm * bf2f(cc[e]) + cl * bf2f(ll[e]) + cr * bf2f(rr[e]);
            union { us8 v; unsigned int u[4]; } o;
            #pragma unroll
            for (int i2 = 0; i2 < 4; i2++) o.u[i2] = f2bf2(v[2 * i2], v[2 * i2 + 1]);
            *(us8*)(dst + c * 8) = o.v;
        }
    }
    __syncthreads();

    // ---- phase G (gcn2 MFMA + bias/relu + per-tile column sums)
    f32x4 acc[8][2] = {};
    #pragma unroll
    for (int ks = 0; ks < 4; ks++) {
        #pragma unroll
        for (int nt = 0; nt < 8; nt++) {
            const bf16x8 af = *(const bf16x8*)(A2 + (nt * 16 + m) * 152 + ks * 32 + q * 8);
            acc[nt][0] = __builtin_amdgcn_mfma_f32_16x16x32_bf16(af, bw[ks][0], acc[nt][0], 0, 0, 0);
            acc[nt][1] = __builtin_amdgcn_mfma_f32_16x16x32_bf16(af, bw[ks][1], acc[nt][1], 0, 0, 0);
        }
    }
    {
        const float bb0 = bls2[wave * 32 + m];
        const float bb1 = bls2[wave * 32 + 16 + m];
        float s0 = 0.f, s1 = 0.f;
        #pragma unroll
        for (int nt = 0; nt < 8; nt++)
            #pragma unroll
            for (int rgi = 0; rgi < 4; rgi++) {
                s0 += fmaxf(acc[nt][0][rgi] + bb0, 0.f);
                s1 += fmaxf(acc[nt][1][rgi] + bb1, 0.f);
            }
        s0 += __shfl_xor(s0, 16, 64); s0 += __shfl_xor(s0, 32, 64);
        s1 += __shfl_xor(s1, 16, 64); s1 += __shfl_xor(s1, 32, 64);
        if (lane < 16) {
            atomicAdd(accum + b * 128 + wave * 32 + m, s0);
            atomicAdd(accum + b * 128 + wave * 32 + 16 + m, s1);
        }
    }

    // ---- finisher: last block of the sample does mean + FC
    __threadfence();
    __syncthreads();
    volatile int* flag = (volatile int*)(lds + 512);
    if (tid == 0) {
        unsigned int old = atomicAdd(cnt + b, 1u);
        *flag = (old == 3u) ? 1 : 0;
    }
    __syncthreads();
    if (*flag) {
        float* smf = (float*)lds;   // A2 region dead (all MFMA reads done before syncs)
        if (tid < 128)
            smf[tid] = atomicAdd(accum + b * 128 + tid, 0.0f) * (1.0f / 512.0f);
        __syncthreads();
        if (tid < 64) {
            float a = fcb[tid];
            #pragma unroll 8
            for (int f = 0; f < 128; f++) a += smf[f] * fcw[f * 64 + tid];
            outp[b * 64 + tid] = a;
        }
    }
}

extern "C" void kernel_launch(void* const* d_in, const int* in_sizes, int n_in,
                              void* d_out, int out_size, void* d_ws, size_t ws_size,
                              hipStream_t stream)
{
    const float* x   = (const float*)d_in[0];
    const float* w1  = (const float*)d_in[1];
    const float* b1  = (const float*)d_in[2];
    const float* w2  = (const float*)d_in[3];
    const float* b2  = (const float*)d_in[4];
    const float* g1w = (const float*)d_in[5];
    const float* g1b = (const float*)d_in[6];
    const float* g2w = (const float*)d_in[7];
    const float* g2b = (const float*)d_in[8];
    const float* fw  = (const float*)d_in[9];
    const float* fb  = (const float*)d_in[10];

    char* ws = (char*)d_ws;
    float* accum       = (float*)(ws);                       // [B][128] fp32 = 512 KB
    unsigned int* cnt  = (unsigned int*)(ws + 524288);       // [B] u32 = 4 KB
    float* out = (float*)d_out;

    hipMemsetAsync(d_ws, 0, 524288 + 4096, stream);
    mega<<<NNODES / 128, 256, 0, stream>>>(x, w1, b1, w2, b2,
                                           g1w, g1b, g2w, g2b, fw, fb,
                                           accum, cnt, out);
}

// Round 8
// 486.861 us; speedup vs baseline: 1.1075x; 1.1075x over previous
//
#include <hip/hip_runtime.h>
#include <hip/hip_bf16.h>

// Problem constants
#define B_      1024
#define CIN     9
#define T0_     2048
#define C1_     16
#define C2_     32
#define RT_     512
#define NNODES  (B_ * RT_)     // 524288
#define HID_    128
#define OUTF_   64

typedef __attribute__((ext_vector_type(8))) __bf16 bf16x8;
typedef __attribute__((ext_vector_type(4))) float f32x4;
typedef __attribute__((ext_vector_type(8))) unsigned short us8;

// ---------- helpers ----------
__device__ __forceinline__ float bf2f(unsigned short u) {
    union { unsigned int i; float f; } c; c.i = ((unsigned int)u) << 16; return c.f;
}
// round-half-up bf16 (2 ops)
__device__ __forceinline__ unsigned short f2bf1(float f) {
    union { float f; unsigned int i; } c; c.f = f;
    return (unsigned short)((c.i + 0x8000u) >> 16);
}
// packed pair: low short = bf16(lo), high short = bf16(hi); 2 adds + 1 v_perm
__device__ __forceinline__ unsigned int f2bf2(float lo, float hi) {
    union { float f; unsigned int i; } a, b; a.f = lo; b.f = hi;
    return __builtin_amdgcn_perm(b.i + 0x8000u, a.i + 0x8000u, 0x07060302u);
}
__device__ __forceinline__ float dinv_of(int r) {
    return (r == 0 || r == RT_ - 1) ? 0.70710678118f : 0.57735026919f;
}

// ---------- kernel R: repack all weights into bf16 MFMA fragment order (32 blocks) ----------
// Wb1 (A-op gcn1, W1^T): e=((ft*64)+lane)*8+j = W1[k=(lane>>4)*8+j][f=ft*16+(lane&15)]
// Wb2 (B-op gcn2):       e=((ks*8+ct)*64+lane)*8+j = W2[k=ks*32+(lane>>4)*8+j][f=ct*16+(lane&15)]
// Wc1 (B-op conv1):      e=(ks*64+lane)*8+j: kk=ks*32+(lane>>4)*8+j -> ktap=kk>>4, ci=kk&15;
//                        = (ktap<5 && ci<9) ? w1[co=lane&15][ci][ktap] : 0
// Wc2 (B-op conv2):      e=((ks*2+nt)*64+lane)*8+j: co=nt*16+(lane&15); (ktap<5)?w2[co][ci][ktap]:0
__global__ __launch_bounds__(256) void repack_w(
    const float* __restrict__ W1g, const float* __restrict__ W2g,
    const float* __restrict__ Wc1g, const float* __restrict__ Wc2g,
    unsigned short* __restrict__ Wb1, unsigned short* __restrict__ Wb2,
    unsigned short* __restrict__ Wc1, unsigned short* __restrict__ Wc2)
{
    const int tid = threadIdx.x;
    const int bid = blockIdx.x;
    if (bid < 8) {                                     // W1: 4096 elems, 512/block
        for (int i = tid; i < 512; i += 256) {
            int s = bid * 512 + i;
            int k = s >> 7, f = s & 127;
            int lane = ((k >> 3) << 4) + (f & 15);
            int e = (((f >> 4) * 64) + lane) * 8 + (k & 7);
            Wb1[e] = f2bf1(W1g[s]);
        }
    } else if (bid < 24) {                             // W2: 16384 elems, 1024/block
        for (int i = tid; i < 1024; i += 256) {
            int s = (bid - 8) * 1024 + i;
            int k = s >> 7, f = s & 127;
            int ks = k >> 5, lane = (((k >> 3) & 3) << 4) + (f & 15);
            int e = ((ks * 8 + (f >> 4)) * 64 + lane) * 8 + (k & 7);
            Wb2[e] = f2bf1(W2g[s]);
        }
    } else if (bid < 28) {                             // Wc1: 1536 elems, 384/block
        for (int i = tid; i < 384; i += 256) {
            int e = (bid - 24) * 384 + i;
            int j = e & 7, lane = (e >> 3) & 63, ks = e >> 9;
            int kk = ks * 32 + (lane >> 4) * 8 + j;
            int k = kk >> 4, ci = kk & 15, co = lane & 15;
            Wc1[e] = (k < 5 && ci < CIN) ? f2bf1(Wc1g[(co * CIN + ci) * 5 + k]) : 0;
        }
    } else {                                           // Wc2: 3072 elems, 768/block
        for (int i = tid; i < 768; i += 256) {
            int e = (bid - 28) * 768 + i;
            int j = e & 7, lane = (e >> 3) & 63, nt = (e >> 9) & 1, ks = e >> 10;
            int kk = ks * 32 + (lane >> 4) * 8 + j;
            int k = kk >> 4, ci = kk & 15, co = nt * 16 + (lane & 15);
            Wc2[e] = (k < 5) ? f2bf1(Wc2g[(co * C1_ + ci) * 5 + k]) : 0;
        }
    }
}

// ---------- MEGAKERNEL: conv1+pool -> conv2+pool -> gcn1 -> gcn2 -> mean -> FC tail ----------
// One block per 128-node tile; prebuilt weight fragments (coalesced 16B loads, L2-hot);
// last-finishing block per sample (atomic counter) does mean + FC.
__global__ __launch_bounds__(256, 2) void mega(
    const float* __restrict__ x,             // [B][9][2048] fp32
    const unsigned short* __restrict__ Wc1,  // conv1 B-frags
    const unsigned short* __restrict__ Wc2,  // conv2 B-frags
    const unsigned short* __restrict__ Wb1,  // gcn1 A-frags (W1^T)
    const unsigned short* __restrict__ Wb2,  // gcn2 B-frags
    const float* __restrict__ c1b, const float* __restrict__ c2b,
    const float* __restrict__ g1b, const float* __restrict__ g2b,
    const float* __restrict__ fcw, const float* __restrict__ fcb,
    float* __restrict__ accum,               // [B][128] fp32, pre-zeroed
    unsigned int* __restrict__ cnt,          // [B] u32, pre-zeroed
    float* __restrict__ outp)                // [B][64] fp32
{
    // LDS lifetime plan (bytes), strides chosen for 2-way-only bank aliasing:
    //   xs    [0, 30912)      552*28 shorts          phases A,B
    //   As1   [0, 11520)      144*40 shorts          phases D,E   (xs dead)
    //   y2loc [11520, 21024)  132*36 shorts          phases C,D
    //   A2    [0, 38912)      128*152 shorts         phases F,G
    //   y1ext [39424, 50624)  280*20 shorts          phases B,C
    //   H     [39424, 74784)  130*136 shorts         phases E,F   (y1ext dead)
    //   bls1  [74784, 75296); bls2 [75296, 75808)
    //   finisher: smf fp32[128] @0, flag int @512    (A2 dead)
    __shared__ __align__(16) unsigned char lds[75808];
    unsigned short* xs    = (unsigned short*)(lds);
    unsigned short* As1   = (unsigned short*)(lds);
    unsigned short* y2loc = (unsigned short*)(lds + 11520);
    unsigned short* A2    = (unsigned short*)(lds);
    unsigned short* y1ext = (unsigned short*)(lds + 39424);
    unsigned short* H     = (unsigned short*)(lds + 39424);
    float* bls1 = (float*)(lds + 74784);
    float* bls2 = (float*)(lds + 75296);

    const int tid = threadIdx.x;
    const int b = blockIdx.x >> 2;
    const int r0 = (blockIdx.x & 3) * 128;
    if (tid < 128) { bls1[tid] = g1b[tid]; bls2[tid] = g2b[tid]; }

    const int lane = tid & 63, wave = tid >> 6;
    const int m = lane & 15, q = lane >> 4;

    // prebuilt conv fragments: coalesced 16B loads
    bf16x8 wfB[3];
    #pragma unroll
    for (int ks = 0; ks < 3; ks++) wfB[ks] = *(const bf16x8*)(Wc1 + (ks * 64 + lane) * 8);
    bf16x8 wfC[3][2];
    #pragma unroll
    for (int ks = 0; ks < 3; ks++)
        #pragma unroll
        for (int nt = 0; nt < 2; nt++)
            wfC[ks][nt] = *(const bf16x8*)(Wc2 + ((ks * 2 + nt) * 64 + lane) * 8);

    // ---- phase A: stage x as bf16 time-major: xs[s][ci], s=0..551, xt=4r0-14+s
    {
        const float* xb = x + (size_t)b * CIN * T0_;
        const int xbase = 4 * r0 - 14;
        for (int s = tid; s < 552; s += 256) {
            const int xt = xbase + s;
            union { us8 v; unsigned int u[4]; } o0, o1;
            if (xt >= 0 && xt < T0_) {
                float xv[9];
                #pragma unroll
                for (int ci = 0; ci < 9; ci++) xv[ci] = xb[ci * T0_ + xt];
                o0.u[0] = f2bf2(xv[0], xv[1]); o0.u[1] = f2bf2(xv[2], xv[3]);
                o0.u[2] = f2bf2(xv[4], xv[5]); o0.u[3] = f2bf2(xv[6], xv[7]);
                o1.u[0] = f2bf2(xv[8], 0.f);   o1.u[1] = o1.u[2] = o1.u[3] = 0;
            } else {
                o0.u[0] = o0.u[1] = o0.u[2] = o0.u[3] = 0;
                o1.u[0] = o1.u[1] = o1.u[2] = o1.u[3] = 0;
            }
            *(us8*)(xs + s * 28) = o0.v;
            *(us8*)(xs + s * 28 + 8) = o1.v;
        }
    }
    __syncthreads();

    // ---- phase B: conv1 MFMA + relu + pool -> y1ext (zero for t1 outside [0,1024))
    {
        const float bv = c1b[m];
        const int t1base = 2 * r0 - 6;
        for (int mt = wave; mt < 34; mt += 4) {
            f32x4 acc = {};
            #pragma unroll
            for (int ks = 0; ks < 3; ks++) {
                const int row = mt * 16 + m + ks * 2 + (q >> 1);
                const bf16x8 af = *(const bf16x8*)(xs + row * 28 + (q & 1) * 8);
                acc = __builtin_amdgcn_mfma_f32_16x16x32_bf16(af, wfB[ks], acc, 0, 0, 0);
            }
            const int prow = mt * 8 + q * 2;     // y1ext row; t1 = t1base + prow
            const int t1a = t1base + prow, t1b = t1a + 1;
            const float p0 = fmaxf(fmaxf(acc[0], acc[1]) + bv, 0.f);
            const float p1 = fmaxf(fmaxf(acc[2], acc[3]) + bv, 0.f);
            if (prow < 268)
                y1ext[prow * 20 + m] = (t1a >= 0 && t1a < 1024) ? f2bf1(p0) : (unsigned short)0;
            if (prow + 1 < 268)
                y1ext[(prow + 1) * 20 + m] = (t1b >= 0 && t1b < 1024) ? f2bf1(p1) : (unsigned short)0;
        }
        for (int idx = tid; idx < 240; idx += 256) y1ext[268 * 20 + idx] = 0;  // rows 268..279
    }
    __syncthreads();

    // ---- phase C: conv2 MFMA + relu + pool -> y2loc (132 nodes: r0-2 .. r0+129)
    {
        const float bv0 = c2b[m], bv1 = c2b[16 + m];
        for (int mt = wave; mt < 17; mt += 4) {
            f32x4 a0 = {}, a1 = {};
            #pragma unroll
            for (int ks = 0; ks < 3; ks++) {
                const int row = mt * 16 + m + ks * 2 + (q >> 1);
                const bf16x8 af = *(const bf16x8*)(y1ext + row * 20 + (q & 1) * 8);
                a0 = __builtin_amdgcn_mfma_f32_16x16x32_bf16(af, wfC[ks][0], a0, 0, 0, 0);
                a1 = __builtin_amdgcn_mfma_f32_16x16x32_bf16(af, wfC[ks][1], a1, 0, 0, 0);
            }
            const int nrow = mt * 8 + q * 2;
            if (nrow < 132) {
                y2loc[nrow * 36 + m]      = f2bf1(fmaxf(fmaxf(a0[0], a0[1]) + bv0, 0.f));
                y2loc[nrow * 36 + 16 + m] = f2bf1(fmaxf(fmaxf(a1[0], a1[1]) + bv1, 0.f));
            }
            if (nrow + 1 < 132) {
                y2loc[(nrow + 1) * 36 + m]      = f2bf1(fmaxf(fmaxf(a0[2], a0[3]) + bv0, 0.f));
                y2loc[(nrow + 1) * 36 + 16 + m] = f2bf1(fmaxf(fmaxf(a1[2], a1[3]) + bv1, 0.f));
            }
        }
    }
    // gcn1 A-frags (prebuilt, coalesced) while conv2 drains
    bf16x8 wfE[2];
    {
        const int ft0 = wave * 2;
        wfE[0] = *(const bf16x8*)(Wb1 + (ft0 * 64 + lane) * 8);
        wfE[1] = *(const bf16x8*)(Wb1 + ((ft0 + 1) * 64 + lane) * 8);
    }
    __syncthreads();

    // ---- phase D (gcn step1): As1 row i <-> node r0-1+i (i<130), stencil from y2loc
    for (int s = tid; s < 288; s += 256) {
        const int i = s >> 1, fh = (s & 1) * 16;
        unsigned short* dst = As1 + i * 40 + fh;
        const int r = r0 - 1 + i;
        union { us8 v; unsigned int u[4]; } o0, o1;
        if (i >= 130 || r < 0 || r >= RT_) {
            o0.u[0] = o0.u[1] = o0.u[2] = o0.u[3] = 0;
            o1.u[0] = o1.u[1] = o1.u[2] = o1.u[3] = 0;
        } else {
            const float dm = dinv_of(r), cm = dm * dm;
            const unsigned short* Yc = y2loc + (i + 1) * 36 + fh;
            us8 c0 = *(const us8*)(Yc), c1 = *(const us8*)(Yc + 8);
            float v[16];
            #pragma unroll
            for (int j = 0; j < 8; j++) { v[j] = cm * bf2f(c0[j]); v[8 + j] = cm * bf2f(c1[j]); }
            if (r > 0) {
                const float cl = dm * dinv_of(r - 1);
                us8 a0 = *(const us8*)(Yc - 36), a1 = *(const us8*)(Yc - 28);
                #pragma unroll
                for (int j = 0; j < 8; j++) { v[j] += cl * bf2f(a0[j]); v[8 + j] += cl * bf2f(a1[j]); }
            }
            if (r < RT_ - 1) {
                const float cr = dm * dinv_of(r + 1);
                us8 a0 = *(const us8*)(Yc + 36), a1 = *(const us8*)(Yc + 44);
                #pragma unroll
                for (int j = 0; j < 8; j++) { v[j] += cr * bf2f(a0[j]); v[8 + j] += cr * bf2f(a1[j]); }
            }
            #pragma unroll
            for (int i2 = 0; i2 < 4; i2++) {
                o0.u[i2] = f2bf2(v[2 * i2], v[2 * i2 + 1]);
                o1.u[i2] = f2bf2(v[8 + 2 * i2], v[9 + 2 * i2]);
            }
        }
        *(us8*)dst = o0.v; *(us8*)(dst + 8) = o1.v;
    }
    // gcn2 B-frags (prebuilt, coalesced) during phase D
    bf16x8 bw[4][2];
    #pragma unroll
    for (int ks = 0; ks < 4; ks++)
        #pragma unroll
        for (int i = 0; i < 2; i++)
            bw[ks][i] = *(const bf16x8*)(Wb2 + ((size_t)((ks * 8 + wave * 2 + i) * 64 + lane)) * 8);
    __syncthreads();

    // ---- phase E (gcn1 MFMA): H = relu(As1 @ W1 + b1), rows 0..129
    {
        const int ft0 = wave * 2;
        const float4 bv0 = *(const float4*)&bls1[ft0 * 16 + q * 4];
        const float4 bv1 = *(const float4*)&bls1[(ft0 + 1) * 16 + q * 4];
        #pragma unroll
        for (int nt = 0; nt < 9; nt++) {
            const bf16x8 bfr = *(const bf16x8*)(As1 + (nt * 16 + m) * 40 + q * 8);
            f32x4 a0 = {}, a1 = {};
            a0 = __builtin_amdgcn_mfma_f32_16x16x32_bf16(wfE[0], bfr, a0, 0, 0, 0);
            a1 = __builtin_amdgcn_mfma_f32_16x16x32_bf16(wfE[1], bfr, a1, 0, 0, 0);
            const int row = nt * 16 + m;
            if (row < 130) {
                union { ushort4 s; unsigned int u[2]; } o0, o1;
                o0.u[0] = f2bf2(fmaxf(a0[0] + bv0.x, 0.f), fmaxf(a0[1] + bv0.y, 0.f));
                o0.u[1] = f2bf2(fmaxf(a0[2] + bv0.z, 0.f), fmaxf(a0[3] + bv0.w, 0.f));
                o1.u[0] = f2bf2(fmaxf(a1[0] + bv1.x, 0.f), fmaxf(a1[1] + bv1.y, 0.f));
                o1.u[1] = f2bf2(fmaxf(a1[2] + bv1.z, 0.f), fmaxf(a1[3] + bv1.w, 0.f));
                *(ushort4*)(H + row * 136 + ft0 * 16 + q * 4) = o0.s;
                *(ushort4*)(H + row * 136 + (ft0 + 1) * 16 + q * 4) = o1.s;
            }
        }
    }
    __syncthreads();

    // ---- phase F (gcn step3): A2[j] = cm*H[j+1] + cl*H[j] + cr*H[j+2], j=0..127
    {
        const int j = tid >> 1, fh = (tid & 1) * 64;
        const int r = r0 + j;
        const float dm = dinv_of(r), cm = dm * dm;
        const float cl = (r > 0) ? dm * dinv_of(r - 1) : 0.f;
        const float cr = (r < RT_ - 1) ? dm * dinv_of(r + 1) : 0.f;
        const unsigned short* Hl = H + j * 136 + fh;
        const unsigned short* Hc = Hl + 136;
        const unsigned short* Hr = Hc + 136;
        unsigned short* dst = A2 + j * 152 + fh;
        #pragma unroll
        for (int c = 0; c < 8; c++) {
            us8 cc = *(const us8*)(Hc + c * 8);
            us8 ll = *(const us8*)(Hl + c * 8);
            us8 rr = *(const us8*)(Hr + c * 8);
            float v[8];
            #pragma unroll
            for (int e = 0; e < 8; e++)
                v[e] = cm * bf2f(cc[e]) + cl * bf2f(ll[e]) + cr * bf2f(rr[e]);
            union { us8 v; unsigned int u[4]; } o;
            #pragma unroll
            for (int i2 = 0; i2 < 4; i2++) o.u[i2] = f2bf2(v[2 * i2], v[2 * i2 + 1]);
            *(us8*)(dst + c * 8) = o.v;
        }
    }
    __syncthreads();

    // ---- phase G (gcn2 MFMA + bias/relu + per-tile column sums)
    f32x4 acc[8][2] = {};
    #pragma unroll
    for (int ks = 0; ks < 4; ks++) {
        #pragma unroll
        for (int nt = 0; nt < 8; nt++) {
            const bf16x8 af = *(const bf16x8*)(A2 + (nt * 16 + m) * 152 + ks * 32 + q * 8);
            acc[nt][0] = __builtin_amdgcn_mfma_f32_16x16x32_bf16(af, bw[ks][0], acc[nt][0], 0, 0, 0);
            acc[nt][1] = __builtin_amdgcn_mfma_f32_16x16x32_bf16(af, bw[ks][1], acc[nt][1], 0, 0, 0);
        }
    }
    {
        const float bb0 = bls2[wave * 32 + m];
        const float bb1 = bls2[wave * 32 + 16 + m];
        float s0 = 0.f, s1 = 0.f;
        #pragma unroll
        for (int nt = 0; nt < 8; nt++)
            #pragma unroll
            for (int rgi = 0; rgi < 4; rgi++) {
                s0 += fmaxf(acc[nt][0][rgi] + bb0, 0.f);
                s1 += fmaxf(acc[nt][1][rgi] + bb1, 0.f);
            }
        s0 += __shfl_xor(s0, 16, 64); s0 += __shfl_xor(s0, 32, 64);
        s1 += __shfl_xor(s1, 16, 64); s1 += __shfl_xor(s1, 32, 64);
        if (lane < 16) {
            atomicAdd(accum + b * 128 + wave * 32 + m, s0);
            atomicAdd(accum + b * 128 + wave * 32 + 16 + m, s1);
        }
    }

    // ---- finisher: last block of the sample does mean + FC
    __threadfence();
    __syncthreads();
    volatile int* flag = (volatile int*)(lds + 512);
    if (tid == 0) {
        unsigned int old = atomicAdd(cnt + b, 1u);
        *flag = (old == 3u) ? 1 : 0;
    }
    __syncthreads();
    if (*flag) {
        float* smf = (float*)lds;   // A2 region dead
        if (tid < 128)
            smf[tid] = atomicAdd(accum + b * 128 + tid, 0.0f) * (1.0f / 512.0f);
        __syncthreads();
        if (tid < 64) {
            float a = fcb[tid];
            #pragma unroll 8
            for (int f = 0; f < 128; f++) a += smf[f] * fcw[f * 64 + tid];
            outp[b * 64 + tid] = a;
        }
    }
}

extern "C" void kernel_launch(void* const* d_in, const int* in_sizes, int n_in,
                              void* d_out, int out_size, void* d_ws, size_t ws_size,
                              hipStream_t stream)
{
    const float* x   = (const float*)d_in[0];
    const float* w1  = (const float*)d_in[1];
    const float* b1  = (const float*)d_in[2];
    const float* w2  = (const float*)d_in[3];
    const float* b2  = (const float*)d_in[4];
    const float* g1w = (const float*)d_in[5];
    const float* g1b = (const float*)d_in[6];
    const float* g2w = (const float*)d_in[7];
    const float* g2b = (const float*)d_in[8];
    const float* fw  = (const float*)d_in[9];
    const float* fb  = (const float*)d_in[10];

    char* ws = (char*)d_ws;
    float* accum       = (float*)(ws);                            // [B][128] fp32 = 512 KB
    unsigned int* cnt  = (unsigned int*)(ws + 524288);            // [B] u32 = 4 KB
    unsigned short* Wb1 = (unsigned short*)(ws + 528384);         // 4096 elems
    unsigned short* Wb2 = (unsigned short*)(ws + 528384 + 16384); // 16384 elems
    unsigned short* Wc1 = (unsigned short*)(ws + 528384 + 65536); // 1536 elems
    unsigned short* Wc2 = (unsigned short*)(ws + 528384 + 81920); // 3072 elems
    float* out = (float*)d_out;

    hipMemsetAsync(d_ws, 0, 524288 + 4096, stream);
    repack_w<<<32, 256, 0, stream>>>(g1w, g2w, w1, w2, Wb1, Wb2, Wc1, Wc2);
    mega<<<NNODES / 128, 256, 0, stream>>>(x, Wc1, Wc2, Wb1, Wb2,
                                           b1, b2, g1b, g2b, fw, fb,
                                           accum, cnt, out);
}

// Round 9
// 259.566 us; speedup vs baseline: 2.0773x; 1.8757x over previous
//
#include <hip/hip_runtime.h>
#include <hip/hip_bf16.h>

// Problem constants
#define B_      1024
#define CIN     9
#define T0_     2048
#define C1_     16
#define C2_     32
#define RT_     512
#define NNODES  (B_ * RT_)     // 524288
#define HID_    128
#define OUTF_   64

typedef __attribute__((ext_vector_type(8))) __bf16 bf16x8;
typedef __attribute__((ext_vector_type(4))) float f32x4;
typedef __attribute__((ext_vector_type(8))) unsigned short us8;

// ---------- helpers ----------
__device__ __forceinline__ float bf2f(unsigned short u) {
    union { unsigned int i; float f; } c; c.i = ((unsigned int)u) << 16; return c.f;
}
// round-half-up bf16 (2 ops)
__device__ __forceinline__ unsigned short f2bf1(float f) {
    union { float f; unsigned int i; } c; c.f = f;
    return (unsigned short)((c.i + 0x8000u) >> 16);
}
// packed pair: low short = bf16(lo), high short = bf16(hi); 2 adds + 1 v_perm
__device__ __forceinline__ unsigned int f2bf2(float lo, float hi) {
    union { float f; unsigned int i; } a, b; a.f = lo; b.f = hi;
    return __builtin_amdgcn_perm(b.i + 0x8000u, a.i + 0x8000u, 0x07060302u);
}
__device__ __forceinline__ float dinv_of(int r) {
    return (r == 0 || r == RT_ - 1) ? 0.70710678118f : 0.57735026919f;
}

// ---------- kernel R: repack all weights into bf16 MFMA fragment order (32 blocks) ----------
__global__ __launch_bounds__(256) void repack_w(
    const float* __restrict__ W1g, const float* __restrict__ W2g,
    const float* __restrict__ Wc1g, const float* __restrict__ Wc2g,
    unsigned short* __restrict__ Wb1, unsigned short* __restrict__ Wb2,
    unsigned short* __restrict__ Wc1, unsigned short* __restrict__ Wc2)
{
    const int tid = threadIdx.x;
    const int bid = blockIdx.x;
    if (bid < 8) {                                     // W1: 4096 elems, 512/block
        for (int i = tid; i < 512; i += 256) {
            int s = bid * 512 + i;
            int k = s >> 7, f = s & 127;
            int lane = ((k >> 3) << 4) + (f & 15);
            int e = (((f >> 4) * 64) + lane) * 8 + (k & 7);
            Wb1[e] = f2bf1(W1g[s]);
        }
    } else if (bid < 24) {                             // W2: 16384 elems, 1024/block
        for (int i = tid; i < 1024; i += 256) {
            int s = (bid - 8) * 1024 + i;
            int k = s >> 7, f = s & 127;
            int ks = k >> 5, lane = (((k >> 3) & 3) << 4) + (f & 15);
            int e = ((ks * 8 + (f >> 4)) * 64 + lane) * 8 + (k & 7);
            Wb2[e] = f2bf1(W2g[s]);
        }
    } else if (bid < 28) {                             // Wc1: 1536 elems, 384/block
        for (int i = tid; i < 384; i += 256) {
            int e = (bid - 24) * 384 + i;
            int j = e & 7, lane = (e >> 3) & 63, ks = e >> 9;
            int kk = ks * 32 + (lane >> 4) * 8 + j;
            int k = kk >> 4, ci = kk & 15, co = lane & 15;
            Wc1[e] = (k < 5 && ci < CIN) ? f2bf1(Wc1g[(co * CIN + ci) * 5 + k]) : 0;
        }
    } else {                                           // Wc2: 3072 elems, 768/block
        for (int i = tid; i < 768; i += 256) {
            int e = (bid - 28) * 768 + i;
            int j = e & 7, lane = (e >> 3) & 63, nt = (e >> 9) & 1, ks = e >> 10;
            int kk = ks * 32 + (lane >> 4) * 8 + j;
            int k = kk >> 4, ci = kk & 15, co = nt * 16 + (lane & 15);
            Wc2[e] = (k < 5) ? f2bf1(Wc2g[(co * C1_ + ci) * 5 + k]) : 0;
        }
    }
}

// ---------- MEGAKERNEL: conv1+pool -> conv2+pool -> gcn1 -> gcn2 -> per-tile mean partials ----------
// One block per 128-node tile; prebuilt weight fragments (coalesced 16B loads, L2-hot).
// NO device-scope atomics/fences in the epilogue (R7/R8 lesson: per-block __threadfence +
// atomic finisher on 8-XCD gfx950 stretched every block ~4x).
__global__ __launch_bounds__(256, 2) void mega(
    const float* __restrict__ x,             // [B][9][2048] fp32
    const unsigned short* __restrict__ Wc1,  // conv1 B-frags
    const unsigned short* __restrict__ Wc2,  // conv2 B-frags
    const unsigned short* __restrict__ Wb1,  // gcn1 A-frags (W1^T)
    const unsigned short* __restrict__ Wb2,  // gcn2 B-frags
    const float* __restrict__ c1b, const float* __restrict__ c2b,
    const float* __restrict__ g1b, const float* __restrict__ g2b,
    float* __restrict__ partials)            // [B][4][128] fp32
{
    // LDS lifetime plan (bytes), strides chosen for 2-way-only bank aliasing:
    //   xs    [0, 30912)      552*28 shorts          phases A,B
    //   As1   [0, 11520)      144*40 shorts          phases D,E   (xs dead)
    //   y2loc [11520, 21024)  132*36 shorts          phases C,D
    //   A2    [0, 38912)      128*152 shorts         phases F,G
    //   y1ext [39424, 50624)  280*20 shorts          phases B,C
    //   H     [39424, 74784)  130*136 shorts         phases E,F   (y1ext dead)
    //   bls1  [74784, 75296); bls2 [75296, 75808)
    __shared__ __align__(16) unsigned char lds[75808];
    unsigned short* xs    = (unsigned short*)(lds);
    unsigned short* As1   = (unsigned short*)(lds);
    unsigned short* y2loc = (unsigned short*)(lds + 11520);
    unsigned short* A2    = (unsigned short*)(lds);
    unsigned short* y1ext = (unsigned short*)(lds + 39424);
    unsigned short* H     = (unsigned short*)(lds + 39424);
    float* bls1 = (float*)(lds + 74784);
    float* bls2 = (float*)(lds + 75296);

    const int tid = threadIdx.x;
    const int b = blockIdx.x >> 2;
    const int r0 = (blockIdx.x & 3) * 128;
    if (tid < 128) { bls1[tid] = g1b[tid]; bls2[tid] = g2b[tid]; }

    const int lane = tid & 63, wave = tid >> 6;
    const int m = lane & 15, q = lane >> 4;

    // prebuilt conv fragments: coalesced 16B loads
    bf16x8 wfB[3];
    #pragma unroll
    for (int ks = 0; ks < 3; ks++) wfB[ks] = *(const bf16x8*)(Wc1 + (ks * 64 + lane) * 8);
    bf16x8 wfC[3][2];
    #pragma unroll
    for (int ks = 0; ks < 3; ks++)
        #pragma unroll
        for (int nt = 0; nt < 2; nt++)
            wfC[ks][nt] = *(const bf16x8*)(Wc2 + ((ks * 2 + nt) * 64 + lane) * 8);

    // ---- phase A: stage x as bf16 time-major: xs[s][ci], s=0..551, xt=4r0-14+s
    {
        const float* xb = x + (size_t)b * CIN * T0_;
        const int xbase = 4 * r0 - 14;
        for (int s = tid; s < 552; s += 256) {
            const int xt = xbase + s;
            union { us8 v; unsigned int u[4]; } o0, o1;
            if (xt >= 0 && xt < T0_) {
                float xv[9];
                #pragma unroll
                for (int ci = 0; ci < 9; ci++) xv[ci] = xb[ci * T0_ + xt];
                o0.u[0] = f2bf2(xv[0], xv[1]); o0.u[1] = f2bf2(xv[2], xv[3]);
                o0.u[2] = f2bf2(xv[4], xv[5]); o0.u[3] = f2bf2(xv[6], xv[7]);
                o1.u[0] = f2bf2(xv[8], 0.f);   o1.u[1] = o1.u[2] = o1.u[3] = 0;
            } else {
                o0.u[0] = o0.u[1] = o0.u[2] = o0.u[3] = 0;
                o1.u[0] = o1.u[1] = o1.u[2] = o1.u[3] = 0;
            }
            *(us8*)(xs + s * 28) = o0.v;
            *(us8*)(xs + s * 28 + 8) = o1.v;
        }
    }
    __syncthreads();

    // ---- phase B: conv1 MFMA + relu + pool -> y1ext (zero for t1 outside [0,1024))
    {
        const float bv = c1b[m];
        const int t1base = 2 * r0 - 6;
        for (int mt = wave; mt < 34; mt += 4) {
            f32x4 acc = {};
            #pragma unroll
            for (int ks = 0; ks < 3; ks++) {
                const int row = mt * 16 + m + ks * 2 + (q >> 1);
                const bf16x8 af = *(const bf16x8*)(xs + row * 28 + (q & 1) * 8);
                acc = __builtin_amdgcn_mfma_f32_16x16x32_bf16(af, wfB[ks], acc, 0, 0, 0);
            }
            const int prow = mt * 8 + q * 2;     // y1ext row; t1 = t1base + prow
            const int t1a = t1base + prow, t1b = t1a + 1;
            const float p0 = fmaxf(fmaxf(acc[0], acc[1]) + bv, 0.f);
            const float p1 = fmaxf(fmaxf(acc[2], acc[3]) + bv, 0.f);
            if (prow < 268)
                y1ext[prow * 20 + m] = (t1a >= 0 && t1a < 1024) ? f2bf1(p0) : (unsigned short)0;
            if (prow + 1 < 268)
                y1ext[(prow + 1) * 20 + m] = (t1b >= 0 && t1b < 1024) ? f2bf1(p1) : (unsigned short)0;
        }
        for (int idx = tid; idx < 240; idx += 256) y1ext[268 * 20 + idx] = 0;  // rows 268..279
    }
    __syncthreads();

    // ---- phase C: conv2 MFMA + relu + pool -> y2loc (132 nodes: r0-2 .. r0+129)
    {
        const float bv0 = c2b[m], bv1 = c2b[16 + m];
        for (int mt = wave; mt < 17; mt += 4) {
            f32x4 a0 = {}, a1 = {};
            #pragma unroll
            for (int ks = 0; ks < 3; ks++) {
                const int row = mt * 16 + m + ks * 2 + (q >> 1);
                const bf16x8 af = *(const bf16x8*)(y1ext + row * 20 + (q & 1) * 8);
                a0 = __builtin_amdgcn_mfma_f32_16x16x32_bf16(af, wfC[ks][0], a0, 0, 0, 0);
                a1 = __builtin_amdgcn_mfma_f32_16x16x32_bf16(af, wfC[ks][1], a1, 0, 0, 0);
            }
            const int nrow = mt * 8 + q * 2;
            if (nrow < 132) {
                y2loc[nrow * 36 + m]      = f2bf1(fmaxf(fmaxf(a0[0], a0[1]) + bv0, 0.f));
                y2loc[nrow * 36 + 16 + m] = f2bf1(fmaxf(fmaxf(a1[0], a1[1]) + bv1, 0.f));
            }
            if (nrow + 1 < 132) {
                y2loc[(nrow + 1) * 36 + m]      = f2bf1(fmaxf(fmaxf(a0[2], a0[3]) + bv0, 0.f));
                y2loc[(nrow + 1) * 36 + 16 + m] = f2bf1(fmaxf(fmaxf(a1[2], a1[3]) + bv1, 0.f));
            }
        }
    }
    // gcn1 A-frags (prebuilt, coalesced) while conv2 drains
    bf16x8 wfE[2];
    {
        const int ft0 = wave * 2;
        wfE[0] = *(const bf16x8*)(Wb1 + (ft0 * 64 + lane) * 8);
        wfE[1] = *(const bf16x8*)(Wb1 + ((ft0 + 1) * 64 + lane) * 8);
    }
    __syncthreads();

    // ---- phase D (gcn step1): As1 row i <-> node r0-1+i (i<130), stencil from y2loc
    for (int s = tid; s < 288; s += 256) {
        const int i = s >> 1, fh = (s & 1) * 16;
        unsigned short* dst = As1 + i * 40 + fh;
        const int r = r0 - 1 + i;
        union { us8 v; unsigned int u[4]; } o0, o1;
        if (i >= 130 || r < 0 || r >= RT_) {
            o0.u[0] = o0.u[1] = o0.u[2] = o0.u[3] = 0;
            o1.u[0] = o1.u[1] = o1.u[2] = o1.u[3] = 0;
        } else {
            const float dm = dinv_of(r), cm = dm * dm;
            const unsigned short* Yc = y2loc + (i + 1) * 36 + fh;
            us8 c0 = *(const us8*)(Yc), c1 = *(const us8*)(Yc + 8);
            float v[16];
            #pragma unroll
            for (int j = 0; j < 8; j++) { v[j] = cm * bf2f(c0[j]); v[8 + j] = cm * bf2f(c1[j]); }
            if (r > 0) {
                const float cl = dm * dinv_of(r - 1);
                us8 a0 = *(const us8*)(Yc - 36), a1 = *(const us8*)(Yc - 28);
                #pragma unroll
                for (int j = 0; j < 8; j++) { v[j] += cl * bf2f(a0[j]); v[8 + j] += cl * bf2f(a1[j]); }
            }
            if (r < RT_ - 1) {
                const float cr = dm * dinv_of(r + 1);
                us8 a0 = *(const us8*)(Yc + 36), a1 = *(const us8*)(Yc + 44);
                #pragma unroll
                for (int j = 0; j < 8; j++) { v[j] += cr * bf2f(a0[j]); v[8 + j] += cr * bf2f(a1[j]); }
            }
            #pragma unroll
            for (int i2 = 0; i2 < 4; i2++) {
                o0.u[i2] = f2bf2(v[2 * i2], v[2 * i2 + 1]);
                o1.u[i2] = f2bf2(v[8 + 2 * i2], v[9 + 2 * i2]);
            }
        }
        *(us8*)dst = o0.v; *(us8*)(dst + 8) = o1.v;
    }
    // gcn2 B-frags (prebuilt, coalesced) during phase D
    bf16x8 bw[4][2];
    #pragma unroll
    for (int ks = 0; ks < 4; ks++)
        #pragma unroll
        for (int i = 0; i < 2; i++)
            bw[ks][i] = *(const bf16x8*)(Wb2 + ((size_t)((ks * 8 + wave * 2 + i) * 64 + lane)) * 8);
    __syncthreads();

    // ---- phase E (gcn1 MFMA): H = relu(As1 @ W1 + b1), rows 0..129
    {
        const int ft0 = wave * 2;
        const float4 bv0 = *(const float4*)&bls1[ft0 * 16 + q * 4];
        const float4 bv1 = *(const float4*)&bls1[(ft0 + 1) * 16 + q * 4];
        #pragma unroll
        for (int nt = 0; nt < 9; nt++) {
            const bf16x8 bfr = *(const bf16x8*)(As1 + (nt * 16 + m) * 40 + q * 8);
            f32x4 a0 = {}, a1 = {};
            a0 = __builtin_amdgcn_mfma_f32_16x16x32_bf16(wfE[0], bfr, a0, 0, 0, 0);
            a1 = __builtin_amdgcn_mfma_f32_16x16x32_bf16(wfE[1], bfr, a1, 0, 0, 0);
            const int row = nt * 16 + m;
            if (row < 130) {
                union { ushort4 s; unsigned int u[2]; } o0, o1;
                o0.u[0] = f2bf2(fmaxf(a0[0] + bv0.x, 0.f), fmaxf(a0[1] + bv0.y, 0.f));
                o0.u[1] = f2bf2(fmaxf(a0[2] + bv0.z, 0.f), fmaxf(a0[3] + bv0.w, 0.f));
                o1.u[0] = f2bf2(fmaxf(a1[0] + bv1.x, 0.f), fmaxf(a1[1] + bv1.y, 0.f));
                o1.u[1] = f2bf2(fmaxf(a1[2] + bv1.z, 0.f), fmaxf(a1[3] + bv1.w, 0.f));
                *(ushort4*)(H + row * 136 + ft0 * 16 + q * 4) = o0.s;
                *(ushort4*)(H + row * 136 + (ft0 + 1) * 16 + q * 4) = o1.s;
            }
        }
    }
    __syncthreads();

    // ---- phase F (gcn step3): A2[j] = cm*H[j+1] + cl*H[j] + cr*H[j+2], j=0..127
    {
        const int j = tid >> 1, fh = (tid & 1) * 64;
        const int r = r0 + j;
        const float dm = dinv_of(r), cm = dm * dm;
        const float cl = (r > 0) ? dm * dinv_of(r - 1) : 0.f;
        const float cr = (r < RT_ - 1) ? dm * dinv_of(r + 1) : 0.f;
        const unsigned short* Hl = H + j * 136 + fh;
        const unsigned short* Hc = Hl + 136;
        const unsigned short* Hr = Hc + 136;
        unsigned short* dst = A2 + j * 152 + fh;
        #pragma unroll
        for (int c = 0; c < 8; c++) {
            us8 cc = *(const us8*)(Hc + c * 8);
            us8 ll = *(const us8*)(Hl + c * 8);
            us8 rr = *(const us8*)(Hr + c * 8);
            float v[8];
            #pragma unroll
            for (int e = 0; e < 8; e++)
                v[e] = cm * bf2f(cc[e]) + cl * bf2f(ll[e]) + cr * bf2f(rr[e]);
            union { us8 v; unsigned int u[4]; } o;
            #pragma unroll
            for (int i2 = 0; i2 < 4; i2++) o.u[i2] = f2bf2(v[2 * i2], v[2 * i2 + 1]);
            *(us8*)(dst + c * 8) = o.v;
        }
    }
    __syncthreads();

    // ---- phase G (gcn2 MFMA + bias/relu + per-tile column sums, plain stores)
    f32x4 acc[8][2] = {};
    #pragma unroll
    for (int ks = 0; ks < 4; ks++) {
        #pragma unroll
        for (int nt = 0; nt < 8; nt++) {
            const bf16x8 af = *(const bf16x8*)(A2 + (nt * 16 + m) * 152 + ks * 32 + q * 8);
            acc[nt][0] = __builtin_amdgcn_mfma_f32_16x16x32_bf16(af, bw[ks][0], acc[nt][0], 0, 0, 0);
            acc[nt][1] = __builtin_amdgcn_mfma_f32_16x16x32_bf16(af, bw[ks][1], acc[nt][1], 0, 0, 0);
        }
    }
    {
        const float bb0 = bls2[wave * 32 + m];
        const float bb1 = bls2[wave * 32 + 16 + m];
        float s0 = 0.f, s1 = 0.f;
        #pragma unroll
        for (int nt = 0; nt < 8; nt++)
            #pragma unroll
            for (int rgi = 0; rgi < 4; rgi++) {
                s0 += fmaxf(acc[nt][0][rgi] + bb0, 0.f);
                s1 += fmaxf(acc[nt][1][rgi] + bb1, 0.f);
            }
        s0 += __shfl_xor(s0, 16, 64); s0 += __shfl_xor(s0, 32, 64);
        s1 += __shfl_xor(s1, 16, 64); s1 += __shfl_xor(s1, 32, 64);
        if (lane < 16) {
            float* p = partials + (size_t)blockIdx.x * 128 + wave * 32;
            p[m] = s0;
            p[16 + m] = s1;
        }
    }
}

// ---------- kernel 5: mean over RT + FC ----------
__global__ __launch_bounds__(128) void fc_kernel(
    const float* __restrict__ partials, const float* __restrict__ fw,
    const float* __restrict__ fb, float* __restrict__ out)
{
    __shared__ float sm[128];
    const int b = blockIdx.x, tid = threadIdx.x;
    float s = 0.f;
    #pragma unroll
    for (int t = 0; t < 4; t++) s += partials[((b << 2) + t) * 128 + tid];
    sm[tid] = s * (1.0f / 512.0f);
    __syncthreads();
    if (tid < 64) {
        float acc = fb[tid];
        #pragma unroll 8
        for (int f = 0; f < 128; f++) acc += sm[f] * fw[f * 64 + tid];
        out[b * 64 + tid] = acc;
    }
}

extern "C" void kernel_launch(void* const* d_in, const int* in_sizes, int n_in,
                              void* d_out, int out_size, void* d_ws, size_t ws_size,
                              hipStream_t stream)
{
    const float* x   = (const float*)d_in[0];
    const float* w1  = (const float*)d_in[1];
    const float* b1  = (const float*)d_in[2];
    const float* w2  = (const float*)d_in[3];
    const float* b2  = (const float*)d_in[4];
    const float* g1w = (const float*)d_in[5];
    const float* g1b = (const float*)d_in[6];
    const float* g2w = (const float*)d_in[7];
    const float* g2b = (const float*)d_in[8];
    const float* fw  = (const float*)d_in[9];
    const float* fb  = (const float*)d_in[10];

    char* ws = (char*)d_ws;
    float* partials     = (float*)(ws);                           // [B][4][128] fp32 = 2MB
    unsigned short* Wb1 = (unsigned short*)(ws + 2097152);        // 4096 elems
    unsigned short* Wb2 = (unsigned short*)(ws + 2097152 + 16384);// 16384 elems
    unsigned short* Wc1 = (unsigned short*)(ws + 2097152 + 65536);// 1536 elems
    unsigned short* Wc2 = (unsigned short*)(ws + 2097152 + 81920);// 3072 elems
    float* out = (float*)d_out;

    repack_w<<<32, 256, 0, stream>>>(g1w, g2w, w1, w2, Wb1, Wb2, Wc1, Wc2);
    mega<<<NNODES / 128, 256, 0, stream>>>(x, Wc1, Wc2, Wb1, Wb2,
                                           b1, b2, g1b, g2b, partials);
    fc_kernel<<<B_, 128, 0, stream>>>(partials, fw, fb, out);
}

// Round 10
// 210.268 us; speedup vs baseline: 2.5643x; 1.2345x over previous
//
#include <hip/hip_runtime.h>
#include <hip/hip_bf16.h>

// Problem constants
#define B_      1024
#define CIN     9
#define T0_     2048
#define C1_     16
#define C2_     32
#define RT_     512
#define NNODES  (B_ * RT_)     // 524288
#define HID_    128
#define OUTF_   64

typedef __attribute__((ext_vector_type(8))) __bf16 bf16x8;
typedef __attribute__((ext_vector_type(4))) float f32x4;
typedef __attribute__((ext_vector_type(8))) unsigned short us8;

// ---------- helpers ----------
__device__ __forceinline__ float bf2f(unsigned short u) {
    union { unsigned int i; float f; } c; c.i = ((unsigned int)u) << 16; return c.f;
}
// round-half-up bf16 (2 ops)
__device__ __forceinline__ unsigned short f2bf1(float f) {
    union { float f; unsigned int i; } c; c.f = f;
    return (unsigned short)((c.i + 0x8000u) >> 16);
}
// packed pair: low short = bf16(lo), high short = bf16(hi); 2 adds + 1 v_perm
__device__ __forceinline__ unsigned int f2bf2(float lo, float hi) {
    union { float f; unsigned int i; } a, b; a.f = lo; b.f = hi;
    return __builtin_amdgcn_perm(b.i + 0x8000u, a.i + 0x8000u, 0x07060302u);
}
__device__ __forceinline__ float dinv_of(int r) {
    return (r == 0 || r == RT_ - 1) ? 0.70710678118f : 0.57735026919f;
}

// ---------- kernel R: repack all weights into bf16 MFMA fragment order (32 blocks) ----------
__global__ __launch_bounds__(256) void repack_w(
    const float* __restrict__ W1g, const float* __restrict__ W2g,
    const float* __restrict__ Wc1g, const float* __restrict__ Wc2g,
    unsigned short* __restrict__ Wb1, unsigned short* __restrict__ Wb2,
    unsigned short* __restrict__ Wc1, unsigned short* __restrict__ Wc2)
{
    const int tid = threadIdx.x;
    const int bid = blockIdx.x;
    if (bid < 8) {                                     // W1: 4096 elems, 512/block
        for (int i = tid; i < 512; i += 256) {
            int s = bid * 512 + i;
            int k = s >> 7, f = s & 127;
            int lane = ((k >> 3) << 4) + (f & 15);
            int e = (((f >> 4) * 64) + lane) * 8 + (k & 7);
            Wb1[e] = f2bf1(W1g[s]);
        }
    } else if (bid < 24) {                             // W2: 16384 elems, 1024/block
        for (int i = tid; i < 1024; i += 256) {
            int s = (bid - 8) * 1024 + i;
            int k = s >> 7, f = s & 127;
            int ks = k >> 5, lane = (((k >> 3) & 3) << 4) + (f & 15);
            int e = ((ks * 8 + (f >> 4)) * 64 + lane) * 8 + (k & 7);
            Wb2[e] = f2bf1(W2g[s]);
        }
    } else if (bid < 28) {                             // Wc1: 1536 elems, 384/block
        for (int i = tid; i < 384; i += 256) {
            int e = (bid - 24) * 384 + i;
            int j = e & 7, lane = (e >> 3) & 63, ks = e >> 9;
            int kk = ks * 32 + (lane >> 4) * 8 + j;
            int k = kk >> 4, ci = kk & 15, co = lane & 15;
            Wc1[e] = (k < 5 && ci < CIN) ? f2bf1(Wc1g[(co * CIN + ci) * 5 + k]) : 0;
        }
    } else {                                           // Wc2: 3072 elems, 768/block
        for (int i = tid; i < 768; i += 256) {
            int e = (bid - 28) * 768 + i;
            int j = e & 7, lane = (e >> 3) & 63, nt = (e >> 9) & 1, ks = e >> 10;
            int kk = ks * 32 + (lane >> 4) * 8 + j;
            int k = kk >> 4, ci = kk & 15, co = nt * 16 + (lane & 15);
            Wc2[e] = (k < 5) ? f2bf1(Wc2g[(co * C1_ + ci) * 5 + k]) : 0;
        }
    }
}

// ---------- MEGAKERNEL: conv1+pool -> conv2+pool -> gcn1 -> gcn2 -> per-tile mean partials ----------
// All LDS row strides are 16B multiples (b128 alignment) with dword-stride gcd(.,32)=4
// -> every wave64 b128 access is exactly 2-way bank-aliased (free).
// No device-scope atomics/fences in the epilogue (R7/R8 lesson).
__global__ __launch_bounds__(256, 2) void mega(
    const float* __restrict__ x,             // [B][9][2048] fp32
    const unsigned short* __restrict__ Wc1,  // conv1 B-frags
    const unsigned short* __restrict__ Wc2,  // conv2 B-frags
    const unsigned short* __restrict__ Wb1,  // gcn1 A-frags (W1^T)
    const unsigned short* __restrict__ Wb2,  // gcn2 B-frags
    const float* __restrict__ c1b, const float* __restrict__ c2b,
    const float* __restrict__ g1b, const float* __restrict__ g2b,
    float* __restrict__ partials)            // [B][4][128] fp32
{
    // LDS lifetime plan (bytes); strides in shorts: xs 24, As1 40, y2loc 40, A2 152,
    // y1ext 24, H 136 — all 16B multiples, all 2-way-only bank patterns.
    //   xs    [0, 26496)      552*24    phases A,B
    //   As1   [0, 11520)      144*40    phases D,E   (xs dead)
    //   y2loc [11520, 22080)  132*40    phases C,D
    //   A2    [0, 38912)      128*152   phases F,G
    //   y1ext [39424, 52864)  280*24    phases B,C
    //   H     [39424, 74784)  130*136   phases E,F   (y1ext dead)
    //   bls1  [74784, 75296); bls2 [75296, 75808)
    __shared__ __align__(16) unsigned char lds[75808];
    unsigned short* xs    = (unsigned short*)(lds);
    unsigned short* As1   = (unsigned short*)(lds);
    unsigned short* y2loc = (unsigned short*)(lds + 11520);
    unsigned short* A2    = (unsigned short*)(lds);
    unsigned short* y1ext = (unsigned short*)(lds + 39424);
    unsigned short* H     = (unsigned short*)(lds + 39424);
    float* bls1 = (float*)(lds + 74784);
    float* bls2 = (float*)(lds + 75296);

    const int tid = threadIdx.x;
    const int b = blockIdx.x >> 2;
    const int r0 = (blockIdx.x & 3) * 128;
    if (tid < 128) { bls1[tid] = g1b[tid]; bls2[tid] = g2b[tid]; }

    const int lane = tid & 63, wave = tid >> 6;
    const int m = lane & 15, q = lane >> 4;

    // prebuilt conv fragments: coalesced 16B loads
    bf16x8 wfB[3];
    #pragma unroll
    for (int ks = 0; ks < 3; ks++) wfB[ks] = *(const bf16x8*)(Wc1 + (ks * 64 + lane) * 8);
    bf16x8 wfC[3][2];
    #pragma unroll
    for (int ks = 0; ks < 3; ks++)
        #pragma unroll
        for (int nt = 0; nt < 2; nt++)
            wfC[ks][nt] = *(const bf16x8*)(Wc2 + ((ks * 2 + nt) * 64 + lane) * 8);

    // ---- phase A: stage x as bf16 time-major: xs[s][ci], s=0..551, xt=4r0-14+s
    {
        const float* xb = x + (size_t)b * CIN * T0_;
        const int xbase = 4 * r0 - 14;
        for (int s = tid; s < 552; s += 256) {
            const int xt = xbase + s;
            union { us8 v; unsigned int u[4]; } o0, o1;
            if (xt >= 0 && xt < T0_) {
                float xv[9];
                #pragma unroll
                for (int ci = 0; ci < 9; ci++) xv[ci] = xb[ci * T0_ + xt];
                o0.u[0] = f2bf2(xv[0], xv[1]); o0.u[1] = f2bf2(xv[2], xv[3]);
                o0.u[2] = f2bf2(xv[4], xv[5]); o0.u[3] = f2bf2(xv[6], xv[7]);
                o1.u[0] = f2bf2(xv[8], 0.f);   o1.u[1] = o1.u[2] = o1.u[3] = 0;
            } else {
                o0.u[0] = o0.u[1] = o0.u[2] = o0.u[3] = 0;
                o1.u[0] = o1.u[1] = o1.u[2] = o1.u[3] = 0;
            }
            *(us8*)(xs + s * 24) = o0.v;
            *(us8*)(xs + s * 24 + 8) = o1.v;
        }
    }
    __syncthreads();

    // ---- phase B: conv1 MFMA + relu + pool -> y1ext (zero for t1 outside [0,1024))
    {
        const float bv = c1b[m];
        const int t1base = 2 * r0 - 6;
        for (int mt = wave; mt < 34; mt += 4) {
            f32x4 acc = {};
            #pragma unroll
            for (int ks = 0; ks < 3; ks++) {
                const int row = mt * 16 + m + ks * 2 + (q >> 1);
                const bf16x8 af = *(const bf16x8*)(xs + row * 24 + (q & 1) * 8);
                acc = __builtin_amdgcn_mfma_f32_16x16x32_bf16(af, wfB[ks], acc, 0, 0, 0);
            }
            const int prow = mt * 8 + q * 2;     // y1ext row; t1 = t1base + prow
            const int t1a = t1base + prow, t1b = t1a + 1;
            const float p0 = fmaxf(fmaxf(acc[0], acc[1]) + bv, 0.f);
            const float p1 = fmaxf(fmaxf(acc[2], acc[3]) + bv, 0.f);
            if (prow < 268)
                y1ext[prow * 24 + m] = (t1a >= 0 && t1a < 1024) ? f2bf1(p0) : (unsigned short)0;
            if (prow + 1 < 268)
                y1ext[(prow + 1) * 24 + m] = (t1b >= 0 && t1b < 1024) ? f2bf1(p1) : (unsigned short)0;
        }
        for (int idx = tid; idx < 288; idx += 256) y1ext[268 * 24 + idx] = 0;  // rows 268..279
    }
    __syncthreads();

    // ---- phase C: conv2 MFMA + relu + pool -> y2loc (132 nodes: r0-2 .. r0+129)
    {
        const float bv0 = c2b[m], bv1 = c2b[16 + m];
        for (int mt = wave; mt < 17; mt += 4) {
            f32x4 a0 = {}, a1 = {};
            #pragma unroll
            for (int ks = 0; ks < 3; ks++) {
                const int row = mt * 16 + m + ks * 2 + (q >> 1);
                const bf16x8 af = *(const bf16x8*)(y1ext + row * 24 + (q & 1) * 8);
                a0 = __builtin_amdgcn_mfma_f32_16x16x32_bf16(af, wfC[ks][0], a0, 0, 0, 0);
                a1 = __builtin_amdgcn_mfma_f32_16x16x32_bf16(af, wfC[ks][1], a1, 0, 0, 0);
            }
            const int nrow = mt * 8 + q * 2;
            if (nrow < 132) {
                y2loc[nrow * 40 + m]      = f2bf1(fmaxf(fmaxf(a0[0], a0[1]) + bv0, 0.f));
                y2loc[nrow * 40 + 16 + m] = f2bf1(fmaxf(fmaxf(a1[0], a1[1]) + bv1, 0.f));
            }
            if (nrow + 1 < 132) {
                y2loc[(nrow + 1) * 40 + m]      = f2bf1(fmaxf(fmaxf(a0[2], a0[3]) + bv0, 0.f));
                y2loc[(nrow + 1) * 40 + 16 + m] = f2bf1(fmaxf(fmaxf(a1[2], a1[3]) + bv1, 0.f));
            }
        }
    }
    // gcn1 A-frags (prebuilt, coalesced) while conv2 drains
    bf16x8 wfE[2];
    {
        const int ft0 = wave * 2;
        wfE[0] = *(const bf16x8*)(Wb1 + (ft0 * 64 + lane) * 8);
        wfE[1] = *(const bf16x8*)(Wb1 + ((ft0 + 1) * 64 + lane) * 8);
    }
    __syncthreads();

    // ---- phase D (gcn step1): As1 row i <-> node r0-1+i (i<130), stencil from y2loc
    for (int s = tid; s < 288; s += 256) {
        const int i = s >> 1, fh = (s & 1) * 16;
        unsigned short* dst = As1 + i * 40 + fh;
        const int r = r0 - 1 + i;
        union { us8 v; unsigned int u[4]; } o0, o1;
        if (i >= 130 || r < 0 || r >= RT_) {
            o0.u[0] = o0.u[1] = o0.u[2] = o0.u[3] = 0;
            o1.u[0] = o1.u[1] = o1.u[2] = o1.u[3] = 0;
        } else {
            const float dm = dinv_of(r), cm = dm * dm;
            const unsigned short* Yc = y2loc + (i + 1) * 40 + fh;
            us8 c0 = *(const us8*)(Yc), c1 = *(const us8*)(Yc + 8);
            float v[16];
            #pragma unroll
            for (int j = 0; j < 8; j++) { v[j] = cm * bf2f(c0[j]); v[8 + j] = cm * bf2f(c1[j]); }
            if (r > 0) {
                const float cl = dm * dinv_of(r - 1);
                us8 a0 = *(const us8*)(Yc - 40), a1 = *(const us8*)(Yc - 32);
                #pragma unroll
                for (int j = 0; j < 8; j++) { v[j] += cl * bf2f(a0[j]); v[8 + j] += cl * bf2f(a1[j]); }
            }
            if (r < RT_ - 1) {
                const float cr = dm * dinv_of(r + 1);
                us8 a0 = *(const us8*)(Yc + 40), a1 = *(const us8*)(Yc + 48);
                #pragma unroll
                for (int j = 0; j < 8; j++) { v[j] += cr * bf2f(a0[j]); v[8 + j] += cr * bf2f(a1[j]); }
            }
            #pragma unroll
            for (int i2 = 0; i2 < 4; i2++) {
                o0.u[i2] = f2bf2(v[2 * i2], v[2 * i2 + 1]);
                o1.u[i2] = f2bf2(v[8 + 2 * i2], v[9 + 2 * i2]);
            }
        }
        *(us8*)dst = o0.v; *(us8*)(dst + 8) = o1.v;
    }
    // gcn2 B-frags (prebuilt, coalesced) during phase D
    bf16x8 bw[4][2];
    #pragma unroll
    for (int ks = 0; ks < 4; ks++)
        #pragma unroll
        for (int i = 0; i < 2; i++)
            bw[ks][i] = *(const bf16x8*)(Wb2 + ((size_t)((ks * 8 + wave * 2 + i) * 64 + lane)) * 8);
    __syncthreads();

    // ---- phase E (gcn1 MFMA): H = relu(As1 @ W1 + b1), rows 0..129
    {
        const int ft0 = wave * 2;
        const float4 bv0 = *(const float4*)&bls1[ft0 * 16 + q * 4];
        const float4 bv1 = *(const float4*)&bls1[(ft0 + 1) * 16 + q * 4];
        #pragma unroll
        for (int nt = 0; nt < 9; nt++) {
            const bf16x8 bfr = *(const bf16x8*)(As1 + (nt * 16 + m) * 40 + q * 8);
            f32x4 a0 = {}, a1 = {};
            a0 = __builtin_amdgcn_mfma_f32_16x16x32_bf16(wfE[0], bfr, a0, 0, 0, 0);
            a1 = __builtin_amdgcn_mfma_f32_16x16x32_bf16(wfE[1], bfr, a1, 0, 0, 0);
            const int row = nt * 16 + m;
            if (row < 130) {
                union { ushort4 s; unsigned int u[2]; } o0, o1;
                o0.u[0] = f2bf2(fmaxf(a0[0] + bv0.x, 0.f), fmaxf(a0[1] + bv0.y, 0.f));
                o0.u[1] = f2bf2(fmaxf(a0[2] + bv0.z, 0.f), fmaxf(a0[3] + bv0.w, 0.f));
                o1.u[0] = f2bf2(fmaxf(a1[0] + bv1.x, 0.f), fmaxf(a1[1] + bv1.y, 0.f));
                o1.u[1] = f2bf2(fmaxf(a1[2] + bv1.z, 0.f), fmaxf(a1[3] + bv1.w, 0.f));
                *(ushort4*)(H + row * 136 + ft0 * 16 + q * 4) = o0.s;
                *(ushort4*)(H + row * 136 + (ft0 + 1) * 16 + q * 4) = o1.s;
            }
        }
    }
    __syncthreads();

    // ---- phase F (gcn step3): A2[j] = cm*H[j+1] + cl*H[j] + cr*H[j+2], j=0..127
    {
        const int j = tid >> 1, fh = (tid & 1) * 64;
        const int r = r0 + j;
        const float dm = dinv_of(r), cm = dm * dm;
        const float cl = (r > 0) ? dm * dinv_of(r - 1) : 0.f;
        const float cr = (r < RT_ - 1) ? dm * dinv_of(r + 1) : 0.f;
        const unsigned short* Hl = H + j * 136 + fh;
        const unsigned short* Hc = Hl + 136;
        const unsigned short* Hr = Hc + 136;
        unsigned short* dst = A2 + j * 152 + fh;
        #pragma unroll
        for (int c = 0; c < 8; c++) {
            us8 cc = *(const us8*)(Hc + c * 8);
            us8 ll = *(const us8*)(Hl + c * 8);
            us8 rr = *(const us8*)(Hr + c * 8);
            float v[8];
            #pragma unroll
            for (int e = 0; e < 8; e++)
                v[e] = cm * bf2f(cc[e]) + cl * bf2f(ll[e]) + cr * bf2f(rr[e]);
            union { us8 v; unsigned int u[4]; } o;
            #pragma unroll
            for (int i2 = 0; i2 < 4; i2++) o.u[i2] = f2bf2(v[2 * i2], v[2 * i2 + 1]);
            *(us8*)(dst + c * 8) = o.v;
        }
    }
    __syncthreads();

    // ---- phase G (gcn2 MFMA + bias/relu + per-tile column sums, plain stores)
    f32x4 acc[8][2] = {};
    #pragma unroll
    for (int ks = 0; ks < 4; ks++) {
        #pragma unroll
        for (int nt = 0; nt < 8; nt++) {
            const bf16x8 af = *(const bf16x8*)(A2 + (nt * 16 + m) * 152 + ks * 32 + q * 8);
            acc[nt][0] = __builtin_amdgcn_mfma_f32_16x16x32_bf16(af, bw[ks][0], acc[nt][0], 0, 0, 0);
            acc[nt][1] = __builtin_amdgcn_mfma_f32_16x16x32_bf16(af, bw[ks][1], acc[nt][1], 0, 0, 0);
        }
    }
    {
        const float bb0 = bls2[wave * 32 + m];
        const float bb1 = bls2[wave * 32 + 16 + m];
        float s0 = 0.f, s1 = 0.f;
        #pragma unroll
        for (int nt = 0; nt < 8; nt++)
            #pragma unroll
            for (int rgi = 0; rgi < 4; rgi++) {
                s0 += fmaxf(acc[nt][0][rgi] + bb0, 0.f);
                s1 += fmaxf(acc[nt][1][rgi] + bb1, 0.f);
            }
        s0 += __shfl_xor(s0, 16, 64); s0 += __shfl_xor(s0, 32, 64);
        s1 += __shfl_xor(s1, 16, 64); s1 += __shfl_xor(s1, 32, 64);
        if (lane < 16) {
            float* p = partials + (size_t)blockIdx.x * 128 + wave * 32;
            p[m] = s0;
            p[16 + m] = s1;
        }
    }
}

// ---------- kernel 5: mean over RT + FC ----------
__global__ __launch_bounds__(128) void fc_kernel(
    const float* __restrict__ partials, const float* __restrict__ fw,
    const float* __restrict__ fb, float* __restrict__ out)
{
    __shared__ float sm[128];
    const int b = blockIdx.x, tid = threadIdx.x;
    float s = 0.f;
    #pragma unroll
    for (int t = 0; t < 4; t++) s += partials[((b << 2) + t) * 128 + tid];
    sm[tid] = s * (1.0f / 512.0f);
    __syncthreads();
    if (tid < 64) {
        float acc = fb[tid];
        #pragma unroll 8
        for (int f = 0; f < 128; f++) acc += sm[f] * fw[f * 64 + tid];
        out[b * 64 + tid] = acc;
    }
}

extern "C" void kernel_launch(void* const* d_in, const int* in_sizes, int n_in,
                              void* d_out, int out_size, void* d_ws, size_t ws_size,
                              hipStream_t stream)
{
    const float* x   = (const float*)d_in[0];
    const float* w1  = (const float*)d_in[1];
    const float* b1  = (const float*)d_in[2];
    const float* w2  = (const float*)d_in[3];
    const float* b2  = (const float*)d_in[4];
    const float* g1w = (const float*)d_in[5];
    const float* g1b = (const float*)d_in[6];
    const float* g2w = (const float*)d_in[7];
    const float* g2b = (const float*)d_in[8];
    const float* fw  = (const float*)d_in[9];
    const float* fb  = (const float*)d_in[10];

    char* ws = (char*)d_ws;
    float* partials     = (float*)(ws);                           // [B][4][128] fp32 = 2MB
    unsigned short* Wb1 = (unsigned short*)(ws + 2097152);        // 4096 elems
    unsigned short* Wb2 = (unsigned short*)(ws + 2097152 + 16384);// 16384 elems
    unsigned short* Wc1 = (unsigned short*)(ws + 2097152 + 65536);// 1536 elems
    unsigned short* Wc2 = (unsigned short*)(ws + 2097152 + 81920);// 3072 elems
    float* out = (float*)d_out;

    repack_w<<<32, 256, 0, stream>>>(g1w, g2w, w1, w2, Wb1, Wb2, Wc1, Wc2);
    mega<<<NNODES / 128, 256, 0, stream>>>(x, Wc1, Wc2, Wb1, Wb2,
                                           b1, b2, g1b, g2b, partials);
    fc_kernel<<<B_, 128, 0, stream>>>(partials, fw, fb, out);
}

// Round 11
// 193.922 us; speedup vs baseline: 2.7804x; 1.0843x over previous
//
#include <hip/hip_runtime.h>
#include <hip/hip_bf16.h>

// Problem constants
#define B_      1024
#define CIN     9
#define T0_     2048
#define C1_     16
#define C2_     32
#define RT_     512
#define NNODES  (B_ * RT_)     // 524288
#define HID_    128
#define OUTF_   64

typedef __attribute__((ext_vector_type(8))) __bf16 bf16x8;
typedef __attribute__((ext_vector_type(4))) float f32x4;
typedef __attribute__((ext_vector_type(8))) unsigned short us8;

// ---------- helpers ----------
__device__ __forceinline__ float bf2f(unsigned short u) {
    union { unsigned int i; float f; } c; c.i = ((unsigned int)u) << 16; return c.f;
}
// round-half-up bf16 (2 ops)
__device__ __forceinline__ unsigned short f2bf1(float f) {
    union { float f; unsigned int i; } c; c.f = f;
    return (unsigned short)((c.i + 0x8000u) >> 16);
}
// packed pair: low short = bf16(lo), high short = bf16(hi); 2 adds + 1 v_perm
__device__ __forceinline__ unsigned int f2bf2(float lo, float hi) {
    union { float f; unsigned int i; } a, b; a.f = lo; b.f = hi;
    return __builtin_amdgcn_perm(b.i + 0x8000u, a.i + 0x8000u, 0x07060302u);
}
__device__ __forceinline__ float dinv_of(int r) {
    return (r == 0 || r == RT_ - 1) ? 0.70710678118f : 0.57735026919f;
}

// ---------- kernel R: repack all weights into bf16 MFMA fragment order (32 blocks) ----------
__global__ __launch_bounds__(256) void repack_w(
    const float* __restrict__ W1g, const float* __restrict__ W2g,
    const float* __restrict__ Wc1g, const float* __restrict__ Wc2g,
    unsigned short* __restrict__ Wb1, unsigned short* __restrict__ Wb2,
    unsigned short* __restrict__ Wc1, unsigned short* __restrict__ Wc2)
{
    const int tid = threadIdx.x;
    const int bid = blockIdx.x;
    if (bid < 8) {                                     // W1: 4096 elems, 512/block
        for (int i = tid; i < 512; i += 256) {
            int s = bid * 512 + i;
            int k = s >> 7, f = s & 127;
            int lane = ((k >> 3) << 4) + (f & 15);
            int e = (((f >> 4) * 64) + lane) * 8 + (k & 7);
            Wb1[e] = f2bf1(W1g[s]);
        }
    } else if (bid < 24) {                             // W2: 16384 elems, 1024/block
        for (int i = tid; i < 1024; i += 256) {
            int s = (bid - 8) * 1024 + i;
            int k = s >> 7, f = s & 127;
            int ks = k >> 5, lane = (((k >> 3) & 3) << 4) + (f & 15);
            int e = ((ks * 8 + (f >> 4)) * 64 + lane) * 8 + (k & 7);
            Wb2[e] = f2bf1(W2g[s]);
        }
    } else if (bid < 28) {                             // Wc1: 1536 elems, 384/block
        for (int i = tid; i < 384; i += 256) {
            int e = (bid - 24) * 384 + i;
            int j = e & 7, lane = (e >> 3) & 63, ks = e >> 9;
            int kk = ks * 32 + (lane >> 4) * 8 + j;
            int k = kk >> 4, ci = kk & 15, co = lane & 15;
            Wc1[e] = (k < 5 && ci < CIN) ? f2bf1(Wc1g[(co * CIN + ci) * 5 + k]) : 0;
        }
    } else {                                           // Wc2: 3072 elems, 768/block
        for (int i = tid; i < 768; i += 256) {
            int e = (bid - 28) * 768 + i;
            int j = e & 7, lane = (e >> 3) & 63, nt = (e >> 9) & 1, ks = e >> 10;
            int kk = ks * 32 + (lane >> 4) * 8 + j;
            int k = kk >> 4, ci = kk & 15, co = nt * 16 + (lane & 15);
            Wc2[e] = (k < 5) ? f2bf1(Wc2g[(co * C1_ + ci) * 5 + k]) : 0;
        }
    }
}

// ---------- MEGAKERNEL ----------
// R11: LDS diet to 49,856 B -> 3 blocks/CU. Phase F (stencil) and G (gcn2 MFMA)
// interleaved in 4 quarters through a 32-row A2 buffer; acc persists in registers.
__global__ __launch_bounds__(256, 3) void mega(
    const float* __restrict__ x,             // [B][9][2048] fp32
    const unsigned short* __restrict__ Wc1,  // conv1 B-frags
    const unsigned short* __restrict__ Wc2,  // conv2 B-frags
    const unsigned short* __restrict__ Wb1,  // gcn1 A-frags (W1^T)
    const unsigned short* __restrict__ Wb2,  // gcn2 B-frags
    const float* __restrict__ c1b, const float* __restrict__ c2b,
    const float* __restrict__ g1b, const float* __restrict__ g2b,
    float* __restrict__ partials)            // [B][4][128] fp32
{
    // LDS overlay (bytes), all strides 16B multiples:
    //   H     [0, 35360)      130*136 shorts   phases E..G4  (xs/y2loc dead by E)
    //   xs    [0, 26496)      552*24  shorts   A,B
    //   y2loc [0, 10560)      132*40  shorts   C,D
    //   y1ext [35392, 48832)  280*24  shorts   B,C
    //   As1   [35392, 46912)  144*40  shorts   D,E
    //   A2q   [35392, 45120)  32*152  shorts   F_i,G_i (quartered)
    //   bls1  [48832, 49344); bls2 [49344, 49856)
    __shared__ __align__(16) unsigned char lds[49856];
    unsigned short* xs    = (unsigned short*)(lds);
    unsigned short* y2loc = (unsigned short*)(lds);
    unsigned short* H     = (unsigned short*)(lds);
    unsigned short* y1ext = (unsigned short*)(lds + 35392);
    unsigned short* As1   = (unsigned short*)(lds + 35392);
    unsigned short* A2q   = (unsigned short*)(lds + 35392);
    float* bls1 = (float*)(lds + 48832);
    float* bls2 = (float*)(lds + 49344);

    const int tid = threadIdx.x;
    const int b = blockIdx.x >> 2;
    const int r0 = (blockIdx.x & 3) * 128;
    if (tid < 128) { bls1[tid] = g1b[tid]; bls2[tid] = g2b[tid]; }

    const int lane = tid & 63, wave = tid >> 6;
    const int m = lane & 15, q = lane >> 4;

    // prebuilt conv fragments: coalesced 16B loads
    bf16x8 wfB[3];
    #pragma unroll
    for (int ks = 0; ks < 3; ks++) wfB[ks] = *(const bf16x8*)(Wc1 + (ks * 64 + lane) * 8);
    bf16x8 wfC[3][2];
    #pragma unroll
    for (int ks = 0; ks < 3; ks++)
        #pragma unroll
        for (int nt = 0; nt < 2; nt++)
            wfC[ks][nt] = *(const bf16x8*)(Wc2 + ((ks * 2 + nt) * 64 + lane) * 8);

    // ---- phase A: stage x as bf16 time-major: xs[s][ci], s=0..551, xt=4r0-14+s
    {
        const float* xb = x + (size_t)b * CIN * T0_;
        const int xbase = 4 * r0 - 14;
        for (int s = tid; s < 552; s += 256) {
            const int xt = xbase + s;
            union { us8 v; unsigned int u[4]; } o0, o1;
            if (xt >= 0 && xt < T0_) {
                float xv[9];
                #pragma unroll
                for (int ci = 0; ci < 9; ci++) xv[ci] = xb[ci * T0_ + xt];
                o0.u[0] = f2bf2(xv[0], xv[1]); o0.u[1] = f2bf2(xv[2], xv[3]);
                o0.u[2] = f2bf2(xv[4], xv[5]); o0.u[3] = f2bf2(xv[6], xv[7]);
                o1.u[0] = f2bf2(xv[8], 0.f);   o1.u[1] = o1.u[2] = o1.u[3] = 0;
            } else {
                o0.u[0] = o0.u[1] = o0.u[2] = o0.u[3] = 0;
                o1.u[0] = o1.u[1] = o1.u[2] = o1.u[3] = 0;
            }
            *(us8*)(xs + s * 24) = o0.v;
            *(us8*)(xs + s * 24 + 8) = o1.v;
        }
    }
    __syncthreads();

    // ---- phase B: conv1 MFMA + relu + pool -> y1ext (zero for t1 outside [0,1024))
    {
        const float bv = c1b[m];
        const int t1base = 2 * r0 - 6;
        for (int mt = wave; mt < 34; mt += 4) {
            f32x4 acc = {};
            #pragma unroll
            for (int ks = 0; ks < 3; ks++) {
                const int row = mt * 16 + m + ks * 2 + (q >> 1);
                const bf16x8 af = *(const bf16x8*)(xs + row * 24 + (q & 1) * 8);
                acc = __builtin_amdgcn_mfma_f32_16x16x32_bf16(af, wfB[ks], acc, 0, 0, 0);
            }
            const int prow = mt * 8 + q * 2;     // y1ext row; t1 = t1base + prow
            const int t1a = t1base + prow, t1b = t1a + 1;
            const float p0 = fmaxf(fmaxf(acc[0], acc[1]) + bv, 0.f);
            const float p1 = fmaxf(fmaxf(acc[2], acc[3]) + bv, 0.f);
            if (prow < 268)
                y1ext[prow * 24 + m] = (t1a >= 0 && t1a < 1024) ? f2bf1(p0) : (unsigned short)0;
            if (prow + 1 < 268)
                y1ext[(prow + 1) * 24 + m] = (t1b >= 0 && t1b < 1024) ? f2bf1(p1) : (unsigned short)0;
        }
        for (int idx = tid; idx < 288; idx += 256) y1ext[268 * 24 + idx] = 0;  // rows 268..279
    }
    __syncthreads();

    // ---- phase C: conv2 MFMA + relu + pool -> y2loc (132 nodes: r0-2 .. r0+129)
    {
        const float bv0 = c2b[m], bv1 = c2b[16 + m];
        for (int mt = wave; mt < 17; mt += 4) {
            f32x4 a0 = {}, a1 = {};
            #pragma unroll
            for (int ks = 0; ks < 3; ks++) {
                const int row = mt * 16 + m + ks * 2 + (q >> 1);
                const bf16x8 af = *(const bf16x8*)(y1ext + row * 24 + (q & 1) * 8);
                a0 = __builtin_amdgcn_mfma_f32_16x16x32_bf16(af, wfC[ks][0], a0, 0, 0, 0);
                a1 = __builtin_amdgcn_mfma_f32_16x16x32_bf16(af, wfC[ks][1], a1, 0, 0, 0);
            }
            const int nrow = mt * 8 + q * 2;
            if (nrow < 132) {
                y2loc[nrow * 40 + m]      = f2bf1(fmaxf(fmaxf(a0[0], a0[1]) + bv0, 0.f));
                y2loc[nrow * 40 + 16 + m] = f2bf1(fmaxf(fmaxf(a1[0], a1[1]) + bv1, 0.f));
            }
            if (nrow + 1 < 132) {
                y2loc[(nrow + 1) * 40 + m]      = f2bf1(fmaxf(fmaxf(a0[2], a0[3]) + bv0, 0.f));
                y2loc[(nrow + 1) * 40 + 16 + m] = f2bf1(fmaxf(fmaxf(a1[2], a1[3]) + bv1, 0.f));
            }
        }
    }
    // gcn1 A-frags (prebuilt, coalesced) while conv2 drains
    bf16x8 wfE[2];
    {
        const int ft0 = wave * 2;
        wfE[0] = *(const bf16x8*)(Wb1 + (ft0 * 64 + lane) * 8);
        wfE[1] = *(const bf16x8*)(Wb1 + ((ft0 + 1) * 64 + lane) * 8);
    }
    __syncthreads();

    // ---- phase D (gcn step1): As1 row i <-> node r0-1+i (i<130), stencil from y2loc
    for (int s = tid; s < 288; s += 256) {
        const int i = s >> 1, fh = (s & 1) * 16;
        unsigned short* dst = As1 + i * 40 + fh;
        const int r = r0 - 1 + i;
        union { us8 v; unsigned int u[4]; } o0, o1;
        if (i >= 130 || r < 0 || r >= RT_) {
            o0.u[0] = o0.u[1] = o0.u[2] = o0.u[3] = 0;
            o1.u[0] = o1.u[1] = o1.u[2] = o1.u[3] = 0;
        } else {
            const float dm = dinv_of(r), cm = dm * dm;
            const unsigned short* Yc = y2loc + (i + 1) * 40 + fh;
            us8 c0 = *(const us8*)(Yc), c1 = *(const us8*)(Yc + 8);
            float v[16];
            #pragma unroll
            for (int j = 0; j < 8; j++) { v[j] = cm * bf2f(c0[j]); v[8 + j] = cm * bf2f(c1[j]); }
            if (r > 0) {
                const float cl = dm * dinv_of(r - 1);
                us8 a0 = *(const us8*)(Yc - 40), a1 = *(const us8*)(Yc - 32);
                #pragma unroll
                for (int j = 0; j < 8; j++) { v[j] += cl * bf2f(a0[j]); v[8 + j] += cl * bf2f(a1[j]); }
            }
            if (r < RT_ - 1) {
                const float cr = dm * dinv_of(r + 1);
                us8 a0 = *(const us8*)(Yc + 40), a1 = *(const us8*)(Yc + 48);
                #pragma unroll
                for (int j = 0; j < 8; j++) { v[j] += cr * bf2f(a0[j]); v[8 + j] += cr * bf2f(a1[j]); }
            }
            #pragma unroll
            for (int i2 = 0; i2 < 4; i2++) {
                o0.u[i2] = f2bf2(v[2 * i2], v[2 * i2 + 1]);
                o1.u[i2] = f2bf2(v[8 + 2 * i2], v[9 + 2 * i2]);
            }
        }
        *(us8*)dst = o0.v; *(us8*)(dst + 8) = o1.v;
    }
    // gcn2 B-frags (prebuilt, coalesced) during phase D
    bf16x8 bw[4][2];
    #pragma unroll
    for (int ks = 0; ks < 4; ks++)
        #pragma unroll
        for (int i = 0; i < 2; i++)
            bw[ks][i] = *(const bf16x8*)(Wb2 + ((size_t)((ks * 8 + wave * 2 + i) * 64 + lane)) * 8);
    __syncthreads();

    // ---- phase E (gcn1 MFMA): H = relu(As1 @ W1 + b1), rows 0..129
    // NOTE: H overwrites the y2loc region (dead) and beyond; As1 lives at 35392+ (disjoint).
    {
        const int ft0 = wave * 2;
        const float4 bv0 = *(const float4*)&bls1[ft0 * 16 + q * 4];
        const float4 bv1 = *(const float4*)&bls1[(ft0 + 1) * 16 + q * 4];
        #pragma unroll
        for (int nt = 0; nt < 9; nt++) {
            const bf16x8 bfr = *(const bf16x8*)(As1 + (nt * 16 + m) * 40 + q * 8);
            f32x4 a0 = {}, a1 = {};
            a0 = __builtin_amdgcn_mfma_f32_16x16x32_bf16(wfE[0], bfr, a0, 0, 0, 0);
            a1 = __builtin_amdgcn_mfma_f32_16x16x32_bf16(wfE[1], bfr, a1, 0, 0, 0);
            const int row = nt * 16 + m;
            if (row < 130) {
                union { ushort4 s; unsigned int u[2]; } o0, o1;
                o0.u[0] = f2bf2(fmaxf(a0[0] + bv0.x, 0.f), fmaxf(a0[1] + bv0.y, 0.f));
                o0.u[1] = f2bf2(fmaxf(a0[2] + bv0.z, 0.f), fmaxf(a0[3] + bv0.w, 0.f));
                o1.u[0] = f2bf2(fmaxf(a1[0] + bv1.x, 0.f), fmaxf(a1[1] + bv1.y, 0.f));
                o1.u[1] = f2bf2(fmaxf(a1[2] + bv1.z, 0.f), fmaxf(a1[3] + bv1.w, 0.f));
                *(ushort4*)(H + row * 136 + ft0 * 16 + q * 4) = o0.s;
                *(ushort4*)(H + row * 136 + (ft0 + 1) * 16 + q * 4) = o1.s;
            }
        }
    }
    __syncthreads();

    // ---- phases F/G interleaved in 4 quarters: A2q rows 32i..32i+31, then MFMA nt=2i,2i+1
    f32x4 acc[8][2] = {};
    #pragma unroll
    for (int qi = 0; qi < 4; qi++) {
        // F_qi: 32 rows x 8 threads/row; thread covers cols [fh, fh+16)
        {
            const int jl = tid >> 3, fh = (tid & 7) * 16;
            const int j = qi * 32 + jl;
            const int r = r0 + j;
            const float dm = dinv_of(r), cm = dm * dm;
            const float cl = (r > 0) ? dm * dinv_of(r - 1) : 0.f;
            const float cr = (r < RT_ - 1) ? dm * dinv_of(r + 1) : 0.f;
            const unsigned short* Hl = H + j * 136 + fh;
            const unsigned short* Hc = Hl + 136;
            const unsigned short* Hr = Hc + 136;
            unsigned short* dst = A2q + jl * 152 + fh;
            #pragma unroll
            for (int c = 0; c < 2; c++) {
                us8 cc = *(const us8*)(Hc + c * 8);
                us8 ll = *(const us8*)(Hl + c * 8);
                us8 rr = *(const us8*)(Hr + c * 8);
                float v[8];
                #pragma unroll
                for (int e = 0; e < 8; e++)
                    v[e] = cm * bf2f(cc[e]) + cl * bf2f(ll[e]) + cr * bf2f(rr[e]);
                union { us8 v; unsigned int u[4]; } o;
                #pragma unroll
                for (int i2 = 0; i2 < 4; i2++) o.u[i2] = f2bf2(v[2 * i2], v[2 * i2 + 1]);
                *(us8*)(dst + c * 8) = o.v;
            }
        }
        __syncthreads();
        // G_qi: gcn2 MFMA for node-tiles nt = 2qi, 2qi+1 (local A2q rows 0..31)
        #pragma unroll
        for (int ntl = 0; ntl < 2; ntl++) {
            const int nt = qi * 2 + ntl;
            #pragma unroll
            for (int ks = 0; ks < 4; ks++) {
                const bf16x8 af = *(const bf16x8*)(A2q + (ntl * 16 + m) * 152 + ks * 32 + q * 8);
                acc[nt][0] = __builtin_amdgcn_mfma_f32_16x16x32_bf16(af, bw[ks][0], acc[nt][0], 0, 0, 0);
                acc[nt][1] = __builtin_amdgcn_mfma_f32_16x16x32_bf16(af, bw[ks][1], acc[nt][1], 0, 0, 0);
            }
        }
        if (qi < 3) __syncthreads();   // protect A2q before next quarter overwrites
    }

    // ---- epilogue: bias/relu + per-tile column sums, plain stores (no atomics)
    {
        const float bb0 = bls2[wave * 32 + m];
        const float bb1 = bls2[wave * 32 + 16 + m];
        float s0 = 0.f, s1 = 0.f;
        #pragma unroll
        for (int nt = 0; nt < 8; nt++)
            #pragma unroll
            for (int rgi = 0; rgi < 4; rgi++) {
                s0 += fmaxf(acc[nt][0][rgi] + bb0, 0.f);
                s1 += fmaxf(acc[nt][1][rgi] + bb1, 0.f);
            }
        s0 += __shfl_xor(s0, 16, 64); s0 += __shfl_xor(s0, 32, 64);
        s1 += __shfl_xor(s1, 16, 64); s1 += __shfl_xor(s1, 32, 64);
        if (lane < 16) {
            float* p = partials + (size_t)blockIdx.x * 128 + wave * 32;
            p[m] = s0;
            p[16 + m] = s1;
        }
    }
}

// ---------- kernel 5: mean over RT + FC ----------
__global__ __launch_bounds__(128) void fc_kernel(
    const float* __restrict__ partials, const float* __restrict__ fw,
    const float* __restrict__ fb, float* __restrict__ out)
{
    __shared__ float sm[128];
    const int b = blockIdx.x, tid = threadIdx.x;
    float s = 0.f;
    #pragma unroll
    for (int t = 0; t < 4; t++) s += partials[((b << 2) + t) * 128 + tid];
    sm[tid] = s * (1.0f / 512.0f);
    __syncthreads();
    if (tid < 64) {
        float acc = fb[tid];
        #pragma unroll 8
        for (int f = 0; f < 128; f++) acc += sm[f] * fw[f * 64 + tid];
        out[b * 64 + tid] = acc;
    }
}

extern "C" void kernel_launch(void* const* d_in, const int* in_sizes, int n_in,
                              void* d_out, int out_size, void* d_ws, size_t ws_size,
                              hipStream_t stream)
{
    const float* x   = (const float*)d_in[0];
    const float* w1  = (const float*)d_in[1];
    const float* b1  = (const float*)d_in[2];
    const float* w2  = (const float*)d_in[3];
    const float* b2  = (const float*)d_in[4];
    const float* g1w = (const float*)d_in[5];
    const float* g1b = (const float*)d_in[6];
    const float* g2w = (const float*)d_in[7];
    const float* g2b = (const float*)d_in[8];
    const float* fw  = (const float*)d_in[9];
    const float* fb  = (const float*)d_in[10];

    char* ws = (char*)d_ws;
    float* partials     = (float*)(ws);                           // [B][4][128] fp32 = 2MB
    unsigned short* Wb1 = (unsigned short*)(ws + 2097152);        // 4096 elems
    unsigned short* Wb2 = (unsigned short*)(ws + 2097152 + 16384);// 16384 elems
    unsigned short* Wc1 = (unsigned short*)(ws + 2097152 + 65536);// 1536 elems
    unsigned short* Wc2 = (unsigned short*)(ws + 2097152 + 81920);// 3072 elems
    float* out = (float*)d_out;

    repack_w<<<32, 256, 0, stream>>>(g1w, g2w, w1, w2, Wb1, Wb2, Wc1, Wc2);
    mega<<<NNODES / 128, 256, 0, stream>>>(x, Wc1, Wc2, Wb1, Wb2,
                                           b1, b2, g1b, g2b, partials);
    fc_kernel<<<B_, 128, 0, stream>>>(partials, fw, fb, out);
}